// Round 2
// baseline (519.673 us; speedup 1.0000x reference)
//
#include <hip/hip_runtime.h>

typedef unsigned short ushort_t;
using floatx4 = __attribute__((__ext_vector_type__(4))) float;
using bf16x8  = __attribute__((__ext_vector_type__(8))) __bf16;
using ushort4v = __attribute__((__ext_vector_type__(4))) ushort_t;

__device__ __forceinline__ ushort_t f2bf(float f) {
  unsigned int u = __builtin_bit_cast(unsigned int, f);
  u += 0x7FFFu + ((u >> 16) & 1u);   // RNE
  return (ushort_t)(u >> 16);
}
__device__ __forceinline__ float b2f(ushort_t h) {
  unsigned int u = ((unsigned int)h) << 16;
  return __builtin_bit_cast(float, u);
}

// ---------------- cast fp32 -> bf16 ----------------
__global__ void cast_f2b(const float* __restrict__ in, ushort_t* __restrict__ out, int n) {
  int i = (blockIdx.x * blockDim.x + threadIdx.x) * 4;
  if (i < n) {
    float4 v = *reinterpret_cast<const float4*>(&in[i]);
    ushort_t o0 = f2bf(v.x), o1 = f2bf(v.y), o2 = f2bf(v.z), o3 = f2bf(v.w);
    ushort4 o = make_ushort4(o0, o1, o2, o3);
    *reinterpret_cast<ushort4*>(&out[i]) = o;
  }
}

// ---------------- GEMM: C[M,N] = A[M,K] * B[N,K]^T (+bias) ----------------
// A, B bf16 row-major (K contiguous). 128x128 tile, BK=32, 4 waves of 64x64.
template<bool BF16OUT>
__global__ __launch_bounds__(256)
void gemm_bt(const ushort_t* __restrict__ A, const ushort_t* __restrict__ B,
             void* __restrict__ Cout, const float* __restrict__ bias,
             int M, int N, int K) {
  __shared__ ushort_t sA[128][40];   // +8 bf16 pad (16B), rows stay 16B aligned
  __shared__ ushort_t sB[128][40];
  const int m0 = blockIdx.y * 128, n0 = blockIdx.x * 128;
  const int tid = threadIdx.x;
  const int lane = tid & 63, w = tid >> 6;
  const int wm = (w >> 1) * 64, wn = (w & 1) * 64;
  const int grp = lane >> 4, l16 = lane & 15;
  floatx4 acc[4][4] = {};
  const int r = tid >> 2, c = (tid & 3) * 8;   // 64 rows x 4 threads x 8 elems
  const ushort_t* Ap = &A[(size_t)(m0 + r) * K + c];
  const ushort_t* Bp = &B[(size_t)(n0 + r) * K + c];
  for (int k0 = 0; k0 < K; k0 += 32) {
    *reinterpret_cast<uint4*>(&sA[r][c])      = *reinterpret_cast<const uint4*>(Ap + k0);
    *reinterpret_cast<uint4*>(&sA[r + 64][c]) = *reinterpret_cast<const uint4*>(Ap + (size_t)64 * K + k0);
    *reinterpret_cast<uint4*>(&sB[r][c])      = *reinterpret_cast<const uint4*>(Bp + k0);
    *reinterpret_cast<uint4*>(&sB[r + 64][c]) = *reinterpret_cast<const uint4*>(Bp + (size_t)64 * K + k0);
    __syncthreads();
    bf16x8 af[4], bfr[4];
#pragma unroll
    for (int i = 0; i < 4; i++)
      af[i] = *reinterpret_cast<const bf16x8*>(&sA[wm + i * 16 + l16][grp * 8]);
#pragma unroll
    for (int i = 0; i < 4; i++)
      bfr[i] = *reinterpret_cast<const bf16x8*>(&sB[wn + i * 16 + l16][grp * 8]);
#pragma unroll
    for (int i = 0; i < 4; i++)
#pragma unroll
      for (int j = 0; j < 4; j++)
        acc[i][j] = __builtin_amdgcn_mfma_f32_16x16x32_bf16(af[i], bfr[j], acc[i][j], 0, 0, 0);
    __syncthreads();
  }
  // C/D layout (m89/m91 verified): row = grp*4 + reg, col = l16
#pragma unroll
  for (int i = 0; i < 4; i++) {
    const int mb = m0 + wm + i * 16 + grp * 4;
#pragma unroll
    for (int j = 0; j < 4; j++) {
      const int nc = n0 + wn + j * 16 + l16;
      const float bv = bias ? bias[nc] : 0.0f;
#pragma unroll
      for (int rr = 0; rr < 4; rr++) {
        if (BF16OUT)
          ((ushort_t*)Cout)[(size_t)(mb + rr) * N + nc] = f2bf(acc[i][j][rr] + bv);
        else
          ((float*)Cout)[(size_t)(mb + rr) * N + nc] = acc[i][j][rr] + bv;
      }
    }
  }
}

// ---------------- QKV postprocess: RMSNorm(q,k) + rotary, layout for attention ----------------
// one wave per (bh, n) row of D=64. qkv bf16 [B*N][3072].
// q is pre-scaled by 0.125 * log2(e) so flash softmax works in exp2 domain.
__global__ __launch_bounds__(256)
void qkv_post(const ushort_t* __restrict__ qkv, const float* __restrict__ pos,
              const float* __restrict__ qw, const float* __restrict__ kw,
              ushort_t* __restrict__ qr, ushort_t* __restrict__ kr, ushort_t* __restrict__ vt) {
  int wid  = blockIdx.x * 4 + (threadIdx.x >> 6);   // [0, 32*2048)
  int lane = threadIdx.x & 63;
  int bh = wid >> 11;          // b*16 + h
  int n  = wid & 2047;
  int b = bh >> 4, h = bh & 15;
  size_t row = (size_t)(b * 2048 + n) * 3072 + h * 64;
  float q = b2f(qkv[row + lane]);
  float k = b2f(qkv[row + 1024 + lane]);
  float v = b2f(qkv[row + 2048 + lane]);
  float sq = q * q, sk = k * k;
#pragma unroll
  for (int off = 32; off > 0; off >>= 1) {
    sq += __shfl_xor(sq, off);
    sk += __shfl_xor(sk, off);
  }
  q = q * rsqrtf(sq * (1.0f / 64.0f) + 1e-6f) * qw[lane];
  k = k * rsqrtf(sk * (1.0f / 64.0f) + 1e-6f) * kw[lane];
  // rotary: pairs (2i, 2i+1); even lane = real, odd = imag
  float ang = pos[n * 32 + (lane >> 1)];
  float cc = __cosf(ang), ss = __sinf(ang);
  float qp = __shfl_xor(q, 1);
  float kp = __shfl_xor(k, 1);
  float sgn = (lane & 1) ? ss : -ss;
  const float qscale = 0.125f * 1.44269504088896340736f;  // head_dim^-0.5 * log2(e)
  float qo = (q * cc + qp * sgn) * qscale;
  float ko = k * cc + kp * sgn;
  size_t o = (size_t)wid * 64 + lane;              // [bh][n][d]
  qr[o] = f2bf(qo);
  kr[o] = f2bf(ko);
  vt[(size_t)(bh * 64 + lane) * 2048 + n] = f2bf(v);   // v transposed: [bh][d][n]
}

// ---------------- Flash attention: register-only, no LDS, no barriers ----------------
// 4 independent waves/block; each wave owns 16 Q rows (q = q0 + l16).
// S^T = K Q^T so each lane's 16 score regs all belong to one Q row.
// PV: O^T[d][q] = mfma(A=V^T frag, B=P frag) with k<->key map
//   k = 8*grp + j  <->  key = 16*(j>>2) + 4*grp + (j&3)
// which makes P exit softmax already in B-frag layout (no LDS transform).
__global__ __launch_bounds__(256)
void flash_attn(const ushort_t* __restrict__ qr, const ushort_t* __restrict__ kr,
                const ushort_t* __restrict__ vt, ushort_t* __restrict__ aout) {
  const int bh = blockIdx.y;
  const int w = threadIdx.x >> 6, lane = threadIdx.x & 63;
  const int grp = lane >> 4, l16 = lane & 15;
  const int q0 = blockIdx.x * 64 + w * 16;
  const size_t hb = (size_t)bh * 2048 * 64;

  // Q as MFMA B-operand: B[k=d][n=qrow] -> lane holds Q[q0+l16][grp*8 + j]
  const ushort_t* qp = &qr[hb + (size_t)(q0 + l16) * 64 + grp * 8];
  const bf16x8 qa0 = *reinterpret_cast<const bf16x8*>(qp);
  const bf16x8 qa1 = *reinterpret_cast<const bf16x8*>(qp + 32);

  floatx4 o[4] = {};                 // O^T C-layout: d = dt*16 + grp*4 + r, q = l16
  float m = -1e30f, l = 0.f;

  const ushort_t* kbase = &kr[hb + (size_t)l16 * 64 + grp * 8];
  const ushort_t* vbase = &vt[((size_t)bh * 64 + l16) * 2048 + grp * 4];

  for (int k0 = 0; k0 < 2048; k0 += 64) {
    // S^T tiles: 16 keys x 16 qrows each; lane holds key = k0+nt*16+grp*4+r, qrow = q0+l16
    floatx4 s[4];
#pragma unroll
    for (int nt = 0; nt < 4; nt++) {
      const ushort_t* kp = kbase + (size_t)(k0 + nt * 16) * 64;
      floatx4 acc = {};
      acc = __builtin_amdgcn_mfma_f32_16x16x32_bf16(*reinterpret_cast<const bf16x8*>(kp), qa0, acc, 0, 0, 0);
      acc = __builtin_amdgcn_mfma_f32_16x16x32_bf16(*reinterpret_cast<const bf16x8*>(kp + 32), qa1, acc, 0, 0, 0);
      s[nt] = acc;
    }
    // online softmax (exp2 domain; scale pre-folded into q). One row per lane.
    float mx = fmaxf(fmaxf(s[0][0], s[0][1]), fmaxf(s[0][2], s[0][3]));
#pragma unroll
    for (int nt = 1; nt < 4; nt++)
      mx = fmaxf(mx, fmaxf(fmaxf(s[nt][0], s[nt][1]), fmaxf(s[nt][2], s[nt][3])));
    mx = fmaxf(mx, __shfl_xor(mx, 16));
    mx = fmaxf(mx, __shfl_xor(mx, 32));
    const float mnew = fmaxf(m, mx);
    const float alpha = exp2f(m - mnew);
    float p[4][4];
    float rs = 0.f;
#pragma unroll
    for (int nt = 0; nt < 4; nt++)
#pragma unroll
      for (int r = 0; r < 4; r++) {
        float pv = exp2f(s[nt][r] - mnew);
        p[nt][r] = pv;
        rs += pv;
      }
    rs += __shfl_xor(rs, 16);
    rs += __shfl_xor(rs, 32);
    l = l * alpha + rs;
    m = mnew;
#pragma unroll
    for (int dt = 0; dt < 4; dt++) {
      o[dt][0] *= alpha; o[dt][1] *= alpha; o[dt][2] *= alpha; o[dt][3] *= alpha;
    }
    // pack P into B-frags (chunk c covers keys c*32..c*32+31 via nt tiles 2c, 2c+1)
    union { ushort_t u[8]; bf16x8 f; } pf[2];
#pragma unroll
    for (int c = 0; c < 2; c++)
#pragma unroll
      for (int j = 0; j < 4; j++) {
        pf[c].u[j]     = f2bf(p[2 * c][j]);
        pf[c].u[j + 4] = f2bf(p[2 * c + 1][j]);
      }
    // PV: o[dt] += V^T-frag * P-frag
#pragma unroll
    for (int c = 0; c < 2; c++) {
#pragma unroll
      for (int dt = 0; dt < 4; dt++) {
        const ushort_t* vp = vbase + (size_t)dt * 16 * 2048 + k0 + c * 32;
        union { ushort4v h[2]; bf16x8 f; } vv;
        vv.h[0] = *reinterpret_cast<const ushort4v*>(vp);
        vv.h[1] = *reinterpret_cast<const ushort4v*>(vp + 16);
        o[dt] = __builtin_amdgcn_mfma_f32_16x16x32_bf16(vv.f, pf[c].f, o[dt], 0, 0, 0);
      }
    }
  }
  // epilogue: lane holds O^T[d = dt*16 + grp*4 + r][q = q0 + l16]; divide by l, store 4 contiguous d
  const int b = bh >> 4, h = bh & 15;
  const float rl = 1.0f / l;
  const size_t orow = (size_t)(b * 2048 + q0 + l16) * 1024 + h * 64;
#pragma unroll
  for (int dt = 0; dt < 4; dt++) {
    ushort4v ov;
#pragma unroll
    for (int r = 0; r < 4; r++) ov[r] = f2bf(o[dt][r] * rl);
    *reinterpret_cast<ushort4v*>(&aout[orow + dt * 16 + grp * 4]) = ov;
  }
}

extern "C" void kernel_launch(void* const* d_in, const int* in_sizes, int n_in,
                              void* d_out, int out_size, void* d_ws, size_t ws_size,
                              hipStream_t stream) {
  const float* x      = (const float*)d_in[0];   // [2,2048,1024]
  const float* pos    = (const float*)d_in[1];   // [2048,32]
  const float* qkv_w  = (const float*)d_in[2];   // [3072,1024]
  const float* q_nw   = (const float*)d_in[3];   // [64]
  const float* k_nw   = (const float*)d_in[4];   // [64]
  const float* proj_w = (const float*)d_in[5];   // [1024,1024]
  const float* proj_b = (const float*)d_in[6];   // [1024]
  float* out = (float*)d_out;                    // [2,2048,1024] fp32

  // workspace layout (all bf16 = ushort), total 72 MB
  ushort_t* x_b     = (ushort_t*)d_ws;                         // 4096*1024
  ushort_t* qkvw_b  = x_b     + (size_t)4096 * 1024;           // 3072*1024
  ushort_t* projw_b = qkvw_b  + (size_t)3072 * 1024;           // 1024*1024
  ushort_t* qkv_b   = projw_b + (size_t)1024 * 1024;           // 4096*3072
  ushort_t* q_r     = qkv_b   + (size_t)4096 * 3072;           // 32*2048*64
  ushort_t* k_r     = q_r     + (size_t)32 * 2048 * 64;
  ushort_t* v_t     = k_r     + (size_t)32 * 2048 * 64;
  ushort_t* a_out   = v_t     + (size_t)32 * 2048 * 64;        // 4096*1024

  cast_f2b<<<4096 * 1024 / 4 / 256, 256, 0, stream>>>(x, x_b, 4096 * 1024);
  cast_f2b<<<3072 * 1024 / 4 / 256, 256, 0, stream>>>(qkv_w, qkvw_b, 3072 * 1024);
  cast_f2b<<<1024 * 1024 / 4 / 256, 256, 0, stream>>>(proj_w, projw_b, 1024 * 1024);

  // QKV: [4096,3072] = x_b[4096,1024] @ qkv_w[3072,1024]^T   -> bf16
  gemm_bt<true><<<dim3(3072 / 128, 4096 / 128), 256, 0, stream>>>(
      x_b, qkvw_b, (void*)qkv_b, nullptr, 4096, 3072, 1024);

  // RMSNorm + rotary + relayout
  qkv_post<<<(2 * 16 * 2048) / 4, 256, 0, stream>>>(qkv_b, pos, q_nw, k_nw, q_r, k_r, v_t);

  // flash attention: grid (q-tiles, bh); 4 independent waves/block
  flash_attn<<<dim3(2048 / 64, 32), 256, 0, stream>>>(q_r, k_r, v_t, a_out);

  // proj: out[4096,1024] = a_out[4096,1024] @ proj_w[1024,1024]^T + b  -> fp32
  gemm_bt<false><<<dim3(1024 / 128, 4096 / 128), 256, 0, stream>>>(
      a_out, projw_b, (void*)out, proj_b, 4096, 1024, 1024);
}

// Round 3
// 252.673 us; speedup vs baseline: 2.0567x; 2.0567x over previous
//
#include <hip/hip_runtime.h>

typedef unsigned short ushort_t;
using floatx4 = __attribute__((__ext_vector_type__(4))) float;
using bf16x8  = __attribute__((__ext_vector_type__(8))) __bf16;
using ushort4v = __attribute__((__ext_vector_type__(4))) ushort_t;

__device__ __forceinline__ ushort_t f2bf(float f) {
  unsigned int u = __builtin_bit_cast(unsigned int, f);
  u += 0x7FFFu + ((u >> 16) & 1u);   // RNE
  return (ushort_t)(u >> 16);
}
__device__ __forceinline__ ushort_t f2bf_rn(float f) {  // cheap round-nearest (ties away)
  unsigned int u = __builtin_bit_cast(unsigned int, f);
  return (ushort_t)((u + 0x8000u) >> 16);
}
__device__ __forceinline__ float b2f(ushort_t h) {
  unsigned int u = ((unsigned int)h) << 16;
  return __builtin_bit_cast(float, u);
}

// async global->LDS, 16B per lane; lds dest must be wave-uniform base (HW adds lane*16)
__device__ __forceinline__ void gl2lds16(const ushort_t* g, ushort_t* l) {
  __builtin_amdgcn_global_load_lds(
      (const __attribute__((address_space(1))) unsigned int*)g,
      (__attribute__((address_space(3))) unsigned int*)l, 16, 0, 0);
}

// ---------------- cast fp32 -> bf16 ----------------
__global__ void cast_f2b(const float* __restrict__ in, ushort_t* __restrict__ out, int n) {
  int i = (blockIdx.x * blockDim.x + threadIdx.x) * 4;
  if (i < n) {
    float4 v = *reinterpret_cast<const float4*>(&in[i]);
    ushort4 o = make_ushort4(f2bf(v.x), f2bf(v.y), f2bf(v.z), f2bf(v.w));
    *reinterpret_cast<ushort4*>(&out[i]) = o;
  }
}

// ---------------- GEMM: C[M,N] = A[M,K] * B[N,K]^T (+bias) ----------------
// m97 structure: unpadded LDS, global_load_lds width-16 staging, 2 barriers/iter.
template<bool BF16OUT>
__global__ __launch_bounds__(256)
void gemm_bt(const ushort_t* __restrict__ A, const ushort_t* __restrict__ B,
             void* __restrict__ Cout, const float* __restrict__ bias,
             int M, int N, int K) {
  __shared__ ushort_t sA[128 * 32];
  __shared__ ushort_t sB[128 * 32];
  const int m0 = blockIdx.y * 128, n0 = blockIdx.x * 128;
  const int tid = threadIdx.x;
  const int lane = tid & 63, w = tid >> 6;
  const int wm = (w >> 1) * 64, wn = (w & 1) * 64;
  const int grp = lane >> 4, l16 = lane & 15;
  const int r0 = lane >> 2, c0 = (lane & 3) * 8;   // within-chunk row/col for staging
  floatx4 acc[4][4] = {};
  for (int k0 = 0; k0 < K; k0 += 32) {
    __syncthreads();                 // prior iter's LDS reads done before overwrite
#pragma unroll
    for (int i = 0; i < 2; i++) {
      const int j = w * 2 + i;       // chunk 0..7, 16 rows each
      gl2lds16(&A[(size_t)(m0 + j * 16 + r0) * K + k0 + c0], &sA[j * 512]);
      gl2lds16(&B[(size_t)(n0 + j * 16 + r0) * K + k0 + c0], &sB[j * 512]);
    }
    __syncthreads();                 // implicit vmcnt(0) drains staging
    bf16x8 af[4], bfr[4];
#pragma unroll
    for (int i = 0; i < 4; i++)
      af[i] = *reinterpret_cast<const bf16x8*>(&sA[(wm + i * 16 + l16) * 32 + grp * 8]);
#pragma unroll
    for (int i = 0; i < 4; i++)
      bfr[i] = *reinterpret_cast<const bf16x8*>(&sB[(wn + i * 16 + l16) * 32 + grp * 8]);
#pragma unroll
    for (int i = 0; i < 4; i++)
#pragma unroll
      for (int j = 0; j < 4; j++)
        acc[i][j] = __builtin_amdgcn_mfma_f32_16x16x32_bf16(af[i], bfr[j], acc[i][j], 0, 0, 0);
  }
  // C/D layout: row = grp*4 + reg, col = l16
#pragma unroll
  for (int i = 0; i < 4; i++) {
    const int mb = m0 + wm + i * 16 + grp * 4;
#pragma unroll
    for (int j = 0; j < 4; j++) {
      const int nc = n0 + wn + j * 16 + l16;
      const float bv = bias ? bias[nc] : 0.0f;
#pragma unroll
      for (int rr = 0; rr < 4; rr++) {
        if (BF16OUT)
          ((ushort_t*)Cout)[(size_t)(mb + rr) * N + nc] = f2bf(acc[i][j][rr] + bv);
        else
          ((float*)Cout)[(size_t)(mb + rr) * N + nc] = acc[i][j][rr] + bv;
      }
    }
  }
}

// ---------------- QKV postprocess: RMSNorm + rotary; swizzled K/V layouts ----------------
// k_r: element (n,d) stored at row n, pos ((d>>3)^(n&7))*8 + (d&7)   [XOR swizzle, 16B groups]
// v_t: element (d,n) stored at row d, 64-key window n&~63, pos (((n>>3)&7)^(d&7))*8 + (n&7)
// q pre-scaled by 0.125*log2(e) so flash softmax runs in exp2 domain with no max subtraction.
__global__ __launch_bounds__(256)
void qkv_post(const ushort_t* __restrict__ qkv, const float* __restrict__ pos,
              const float* __restrict__ qw, const float* __restrict__ kw,
              ushort_t* __restrict__ qr, ushort_t* __restrict__ kr, ushort_t* __restrict__ vt) {
  int wid  = blockIdx.x * 4 + (threadIdx.x >> 6);   // [0, 32*2048)
  int lane = threadIdx.x & 63;
  int bh = wid >> 11;          // b*16 + h
  int n  = wid & 2047;
  int b = bh >> 4, h = bh & 15;
  size_t row = (size_t)(b * 2048 + n) * 3072 + h * 64;
  float q = b2f(qkv[row + lane]);
  float k = b2f(qkv[row + 1024 + lane]);
  float v = b2f(qkv[row + 2048 + lane]);
  float sq = q * q, sk = k * k;
#pragma unroll
  for (int off = 32; off > 0; off >>= 1) {
    sq += __shfl_xor(sq, off);
    sk += __shfl_xor(sk, off);
  }
  q = q * rsqrtf(sq * (1.0f / 64.0f) + 1e-6f) * qw[lane];
  k = k * rsqrtf(sk * (1.0f / 64.0f) + 1e-6f) * kw[lane];
  float ang = pos[n * 32 + (lane >> 1)];
  float cc = __cosf(ang), ss = __sinf(ang);
  float qp = __shfl_xor(q, 1);
  float kp = __shfl_xor(k, 1);
  float sgn = (lane & 1) ? ss : -ss;
  const float qscale = 0.125f * 1.44269504088896340736f;  // D^-0.5 * log2(e)
  float qo = (q * cc + qp * sgn) * qscale;
  float ko = k * cc + kp * sgn;
  qr[(size_t)wid * 64 + lane] = f2bf(qo);                         // unswizzled
  int kpos = ((lane >> 3) ^ (n & 7)) * 8 + (lane & 7);
  kr[(size_t)wid * 64 + kpos] = f2bf(ko);
  int vg = (((n >> 3) & 7) ^ (lane & 7));
  vt[(size_t)(bh * 64 + lane) * 2048 + (n & ~63) + vg * 8 + (n & 7)] = f2bf(v);
}

// ---------------- Flash attention v3: LDS-staged K/V, double-buffered, no max ----------------
// Block: 4 waves x 16 q-rows = 64 q. K/V 64-key tiles shared across waves via
// global_load_lds (16B). XOR swizzle (baked into k_r/v_t) keeps ds_reads <=2-way.
// Softmax has no running max: ||q||=||k||=8 after RMSNorm => |score*scale*log2e| <= 11.6,
// exp2 safe in fp32 (norm weights are ones for this problem).
__global__ __launch_bounds__(256)
void flash_attn(const ushort_t* __restrict__ qr, const ushort_t* __restrict__ kr,
                const ushort_t* __restrict__ vt, ushort_t* __restrict__ aout) {
  const int bh = blockIdx.y;
  const int w = threadIdx.x >> 6, lane = threadIdx.x & 63;
  const int grp = lane >> 4, l16 = lane & 15;
  const int sw = l16 & 7;
  const int q0 = blockIdx.x * 64 + w * 16;
  const size_t hb = (size_t)bh * 2048 * 64;

  __shared__ ushort_t sK[2][64 * 64];   // [key][d-swizzled], 8KB each
  __shared__ ushort_t sV[2][64 * 64];   // [d][key-swizzled], 8KB each

  // Q as MFMA B-operand: lane holds Q[q0+l16][grp*8 + j]
  const ushort_t* qp = &qr[hb + (size_t)(q0 + l16) * 64 + grp * 8];
  const bf16x8 qa0 = *reinterpret_cast<const bf16x8*>(qp);
  const bf16x8 qa1 = *reinterpret_cast<const bf16x8*>(qp + 32);

  floatx4 o[4] = {};     // O^T C-layout: d = dt*16 + grp*4 + r, q = q0 + l16
  float l = 0.f;         // partial row-sum (this lane's quarter of keys)

  auto stage = [&](int buf, int k0) {
    // K tile: 8KB contiguous in global; 8 chunks of 1KB (wave w: chunks 2w, 2w+1)
    const ushort_t* kg = &kr[hb + (size_t)k0 * 64];
#pragma unroll
    for (int i = 0; i < 2; i++) {
      const int j = w * 2 + i;
      gl2lds16(kg + j * 512 + lane * 8, &sK[buf][j * 512]);
    }
    // V tile: 64 d-rows x 128B; wave w stages d-rows w*16 .. w*16+15
#pragma unroll
    for (int i = 0; i < 2; i++) {
      const int d = w * 16 + i * 8;
      gl2lds16(&vt[((size_t)bh * 64 + d + (lane >> 3)) * 2048 + k0 + (lane & 7) * 8],
               &sV[buf][d * 64]);
    }
  };

  stage(0, 0);
  for (int it = 0; it < 32; it++) {
    const int cur = it & 1;
    __syncthreads();                       // drains staging (vmcnt) + read/write fences
    if (it + 1 < 32) stage(1 - cur, (it + 1) * 64);
    const ushort_t* kb = &sK[cur][0];
    const ushort_t* vb = &sV[cur][0];
    // S^T: lane holds key = nt*16 + grp*4 + r, qrow = q0 + l16
    floatx4 s[4];
#pragma unroll
    for (int nt = 0; nt < 4; nt++) {
      const ushort_t* kp = kb + (nt * 16 + l16) * 64;
      const int g0 = (grp ^ sw) * 8;
      bf16x8 kf0 = *reinterpret_cast<const bf16x8*>(kp + g0);
      bf16x8 kf1 = *reinterpret_cast<const bf16x8*>(kp + (g0 ^ 32));
      floatx4 acc = {};
      acc = __builtin_amdgcn_mfma_f32_16x16x32_bf16(kf0, qa0, acc, 0, 0, 0);
      acc = __builtin_amdgcn_mfma_f32_16x16x32_bf16(kf1, qa1, acc, 0, 0, 0);
      s[nt] = acc;
    }
    // softmax, no max subtraction
    float p[4][4];
    float rs = 0.f;
#pragma unroll
    for (int nt = 0; nt < 4; nt++)
#pragma unroll
      for (int r = 0; r < 4; r++) {
        float pv = exp2f(s[nt][r]);
        p[nt][r] = pv;
        rs += pv;
      }
    l += rs;
    // pack P into B-frags: pf[c].u[j<4] = keys c*32+grp*4+j, u[j>=4] = +16
    union { ushort_t u[8]; bf16x8 f; } pf[2];
#pragma unroll
    for (int c = 0; c < 2; c++)
#pragma unroll
      for (int j = 0; j < 4; j++) {
        pf[c].u[j]     = f2bf_rn(p[2 * c][j]);
        pf[c].u[j + 4] = f2bf_rn(p[2 * c + 1][j]);
      }
    // PV: o[dt] += V^T-frag * P-frag
#pragma unroll
    for (int c = 0; c < 2; c++) {
      const int gb = c * 4 + (grp >> 1);
      const int g1 = (gb ^ sw) * 8 + (grp & 1) * 4;
      const int g2 = ((gb + 2) ^ sw) * 8 + (grp & 1) * 4;
#pragma unroll
      for (int dt = 0; dt < 4; dt++) {
        const ushort_t* vr = vb + (dt * 16 + l16) * 64;
        union { ushort4v h[2]; bf16x8 f; } vv;
        vv.h[0] = *reinterpret_cast<const ushort4v*>(vr + g1);
        vv.h[1] = *reinterpret_cast<const ushort4v*>(vr + g2);
        o[dt] = __builtin_amdgcn_mfma_f32_16x16x32_bf16(vv.f, pf[c].f, o[dt], 0, 0, 0);
      }
    }
  }
  // row-sum across the 4 lanes sharing this q-row, then scale + store
  float lt = l + __shfl_xor(l, 16);
  lt += __shfl_xor(lt, 32);
  const float rl = 1.0f / lt;
  const int b = bh >> 4, h = bh & 15;
  const size_t orow = (size_t)(b * 2048 + q0 + l16) * 1024 + h * 64;
#pragma unroll
  for (int dt = 0; dt < 4; dt++) {
    ushort4v ov;
#pragma unroll
    for (int r = 0; r < 4; r++) ov[r] = f2bf(o[dt][r] * rl);
    *reinterpret_cast<ushort4v*>(&aout[orow + dt * 16 + grp * 4]) = ov;
  }
}

extern "C" void kernel_launch(void* const* d_in, const int* in_sizes, int n_in,
                              void* d_out, int out_size, void* d_ws, size_t ws_size,
                              hipStream_t stream) {
  const float* x      = (const float*)d_in[0];   // [2,2048,1024]
  const float* pos    = (const float*)d_in[1];   // [2048,32]
  const float* qkv_w  = (const float*)d_in[2];   // [3072,1024]
  const float* q_nw   = (const float*)d_in[3];   // [64]
  const float* k_nw   = (const float*)d_in[4];   // [64]
  const float* proj_w = (const float*)d_in[5];   // [1024,1024]
  const float* proj_b = (const float*)d_in[6];   // [1024]
  float* out = (float*)d_out;                    // [2,2048,1024] fp32

  ushort_t* x_b     = (ushort_t*)d_ws;                         // 4096*1024
  ushort_t* qkvw_b  = x_b     + (size_t)4096 * 1024;           // 3072*1024
  ushort_t* projw_b = qkvw_b  + (size_t)3072 * 1024;           // 1024*1024
  ushort_t* qkv_b   = projw_b + (size_t)1024 * 1024;           // 4096*3072
  ushort_t* q_r     = qkv_b   + (size_t)4096 * 3072;           // 32*2048*64
  ushort_t* k_r     = q_r     + (size_t)32 * 2048 * 64;
  ushort_t* v_t     = k_r     + (size_t)32 * 2048 * 64;
  ushort_t* a_out   = v_t     + (size_t)32 * 2048 * 64;        // 4096*1024

  cast_f2b<<<4096 * 1024 / 4 / 256, 256, 0, stream>>>(x, x_b, 4096 * 1024);
  cast_f2b<<<3072 * 1024 / 4 / 256, 256, 0, stream>>>(qkv_w, qkvw_b, 3072 * 1024);
  cast_f2b<<<1024 * 1024 / 4 / 256, 256, 0, stream>>>(proj_w, projw_b, 1024 * 1024);

  gemm_bt<true><<<dim3(3072 / 128, 4096 / 128), 256, 0, stream>>>(
      x_b, qkvw_b, (void*)qkv_b, nullptr, 4096, 3072, 1024);

  qkv_post<<<(2 * 16 * 2048) / 4, 256, 0, stream>>>(qkv_b, pos, q_nw, k_nw, q_r, k_r, v_t);

  flash_attn<<<dim3(2048 / 64, 32), 256, 0, stream>>>(q_r, k_r, v_t, a_out);

  gemm_bt<false><<<dim3(1024 / 128, 4096 / 128), 256, 0, stream>>>(
      a_out, projw_b, (void*)out, proj_b, 4096, 1024, 1024);
}

// Round 4
// 233.973 us; speedup vs baseline: 2.2211x; 1.0799x over previous
//
#include <hip/hip_runtime.h>

typedef unsigned short ushort_t;
using floatx4 = __attribute__((__ext_vector_type__(4))) float;
using bf16x8  = __attribute__((__ext_vector_type__(8))) __bf16;
using ushort4v = __attribute__((__ext_vector_type__(4))) ushort_t;

__device__ __forceinline__ ushort_t f2bf(float f) {
  unsigned int u = __builtin_bit_cast(unsigned int, f);
  u += 0x7FFFu + ((u >> 16) & 1u);   // RNE
  return (ushort_t)(u >> 16);
}
__device__ __forceinline__ ushort_t f2bf_rn(float f) {  // cheap round-nearest (ties away)
  unsigned int u = __builtin_bit_cast(unsigned int, f);
  return (ushort_t)((u + 0x8000u) >> 16);
}
__device__ __forceinline__ float b2f(ushort_t h) {
  unsigned int u = ((unsigned int)h) << 16;
  return __builtin_bit_cast(float, u);
}

// async global->LDS, 16B per lane; lds dest is wave-uniform base (HW adds lane*16)
__device__ __forceinline__ void gl2lds16(const ushort_t* g, ushort_t* l) {
  __builtin_amdgcn_global_load_lds(
      (const __attribute__((address_space(1))) unsigned int*)g,
      (__attribute__((address_space(3))) unsigned int*)l, 16, 0, 0);
}

// ---------------- cast fp32 -> bf16 ----------------
__global__ void cast_f2b(const float* __restrict__ in, ushort_t* __restrict__ out, int n) {
  int i = (blockIdx.x * blockDim.x + threadIdx.x) * 4;
  if (i < n) {
    float4 v = *reinterpret_cast<const float4*>(&in[i]);
    ushort4 o = make_ushort4(f2bf(v.x), f2bf(v.y), f2bf(v.z), f2bf(v.w));
    *reinterpret_cast<ushort4*>(&out[i]) = o;
  }
}

// ---------------- GEMM: C[M,N] = A[M,K] * B[N,K]^T (+bias) ----------------
// m97 structure: unpadded LDS, global_load_lds width-16 staging, 2 barriers/iter.
template<bool BF16OUT>
__global__ __launch_bounds__(256)
void gemm_bt(const ushort_t* __restrict__ A, const ushort_t* __restrict__ B,
             void* __restrict__ Cout, const float* __restrict__ bias,
             int M, int N, int K) {
  __shared__ ushort_t sA[128 * 32];
  __shared__ ushort_t sB[128 * 32];
  const int m0 = blockIdx.y * 128, n0 = blockIdx.x * 128;
  const int tid = threadIdx.x;
  const int lane = tid & 63, w = tid >> 6;
  const int wm = (w >> 1) * 64, wn = (w & 1) * 64;
  const int grp = lane >> 4, l16 = lane & 15;
  const int r0 = lane >> 2, c0 = (lane & 3) * 8;   // within-chunk row/col for staging
  floatx4 acc[4][4] = {};
  for (int k0 = 0; k0 < K; k0 += 32) {
    __syncthreads();                 // prior iter's LDS reads done before overwrite
#pragma unroll
    for (int i = 0; i < 2; i++) {
      const int j = w * 2 + i;       // chunk 0..7, 16 rows each
      gl2lds16(&A[(size_t)(m0 + j * 16 + r0) * K + k0 + c0], &sA[j * 512]);
      gl2lds16(&B[(size_t)(n0 + j * 16 + r0) * K + k0 + c0], &sB[j * 512]);
    }
    __syncthreads();                 // implicit vmcnt(0) drains staging
    bf16x8 af[4], bfr[4];
#pragma unroll
    for (int i = 0; i < 4; i++)
      af[i] = *reinterpret_cast<const bf16x8*>(&sA[(wm + i * 16 + l16) * 32 + grp * 8]);
#pragma unroll
    for (int i = 0; i < 4; i++)
      bfr[i] = *reinterpret_cast<const bf16x8*>(&sB[(wn + i * 16 + l16) * 32 + grp * 8]);
#pragma unroll
    for (int i = 0; i < 4; i++)
#pragma unroll
      for (int j = 0; j < 4; j++)
        acc[i][j] = __builtin_amdgcn_mfma_f32_16x16x32_bf16(af[i], bfr[j], acc[i][j], 0, 0, 0);
  }
  // C/D layout: row = grp*4 + reg, col = l16
#pragma unroll
  for (int i = 0; i < 4; i++) {
    const int mb = m0 + wm + i * 16 + grp * 4;
#pragma unroll
    for (int j = 0; j < 4; j++) {
      const int nc = n0 + wn + j * 16 + l16;
      const float bv = bias ? bias[nc] : 0.0f;
#pragma unroll
      for (int rr = 0; rr < 4; rr++) {
        if (BF16OUT)
          ((ushort_t*)Cout)[(size_t)(mb + rr) * N + nc] = f2bf(acc[i][j][rr] + bv);
        else
          ((float*)Cout)[(size_t)(mb + rr) * N + nc] = acc[i][j][rr] + bv;
      }
    }
  }
}

// ---------------- QKV postprocess: RMSNorm + rotary; swizzled K/V layouts ----------------
// k_r: element (n,d) at row n, pos ((d>>3)^(n&7))*8 + (d&7)   [XOR swizzle, 16B chunks]
// v_t: element (d,n): within 64-key window, key nt*16+g*4+r (nt=(n>>4)&3,g=(n>>2)&3,r=n&3)
//      stored at idx = (nt>>1)*32 + g*8 + (nt&1)*4 + r, chunk-XOR-swizzled by (d&7).
//      This makes each PV A-frag (8 keys/lane) one contiguous 16B LDS read.
// q pre-scaled by 0.125*log2(e) so flash softmax runs in exp2 domain with no max subtraction.
__global__ __launch_bounds__(256)
void qkv_post(const ushort_t* __restrict__ qkv, const float* __restrict__ pos,
              const float* __restrict__ qw, const float* __restrict__ kw,
              ushort_t* __restrict__ qr, ushort_t* __restrict__ kr, ushort_t* __restrict__ vt) {
  int wid  = blockIdx.x * 4 + (threadIdx.x >> 6);   // [0, 32*2048)
  int lane = threadIdx.x & 63;
  int bh = wid >> 11;          // b*16 + h
  int n  = wid & 2047;
  int b = bh >> 4, h = bh & 15;
  size_t row = (size_t)(b * 2048 + n) * 3072 + h * 64;
  float q = b2f(qkv[row + lane]);
  float k = b2f(qkv[row + 1024 + lane]);
  float v = b2f(qkv[row + 2048 + lane]);
  float sq = q * q, sk = k * k;
#pragma unroll
  for (int off = 32; off > 0; off >>= 1) {
    sq += __shfl_xor(sq, off);
    sk += __shfl_xor(sk, off);
  }
  q = q * rsqrtf(sq * (1.0f / 64.0f) + 1e-6f) * qw[lane];
  k = k * rsqrtf(sk * (1.0f / 64.0f) + 1e-6f) * kw[lane];
  float ang = pos[n * 32 + (lane >> 1)];
  float cc = __cosf(ang), ss = __sinf(ang);
  float qp = __shfl_xor(q, 1);
  float kp = __shfl_xor(k, 1);
  float sgn = (lane & 1) ? ss : -ss;
  const float qscale = 0.125f * 1.44269504088896340736f;  // D^-0.5 * log2(e)
  float qo = (q * cc + qp * sgn) * qscale;
  float ko = k * cc + kp * sgn;
  qr[(size_t)wid * 64 + lane] = f2bf(qo);                         // unswizzled
  int kpos = ((lane >> 3) ^ (n & 7)) * 8 + (lane & 7);
  kr[(size_t)wid * 64 + kpos] = f2bf(ko);
  // v_t permuted index
  int nw = n & 63;
  int idx = ((nw >> 5) << 5) + (((nw >> 2) & 3) << 3) + (((nw >> 4) & 1) << 2) + (nw & 3);
  int vpos = (((idx >> 3) ^ (lane & 7)) << 3) + (idx & 7);
  vt[(size_t)(bh * 64 + lane) * 2048 + (n & ~63) + vpos] = f2bf(v);
}

// ---------------- Flash attention v4: 2 Q-frags/wave, LDS K/V shared, dbuf ----------------
// Block: 4 waves x 32 q-rows = 128 q. Each K/V LDS fragment feeds 2 MFMAs (one per
// Q-frag) halving LDS bytes/q vs v3. V reads are single b128 thanks to permuted v_t.
// No running max: ||q||=||k||=8 after RMSNorm => |score*log2e*scale| <= 11.6, exp2-safe.
__global__ __launch_bounds__(256)
void flash_attn(const ushort_t* __restrict__ qr, const ushort_t* __restrict__ kr,
                const ushort_t* __restrict__ vt, ushort_t* __restrict__ aout) {
  const int bh = blockIdx.y;
  const int w = threadIdx.x >> 6, lane = threadIdx.x & 63;
  const int grp = lane >> 4, l16 = lane & 15;
  const int sw = l16 & 7;
  const int q0 = blockIdx.x * 128 + w * 32;
  const size_t hb = (size_t)bh * 2048 * 64;

  __shared__ ushort_t sK[2][64 * 64];   // [key][d-swizzled], 8KB each
  __shared__ ushort_t sV[2][64 * 64];   // [d][key permuted+swizzled], 8KB each

  // Q as MFMA B-operand: lane holds Q[q0 + f*16 + l16][grp*8 + j]
  bf16x8 qa[2][2];
#pragma unroll
  for (int f = 0; f < 2; f++) {
    const ushort_t* qp = &qr[hb + (size_t)(q0 + f * 16 + l16) * 64 + grp * 8];
    qa[f][0] = *reinterpret_cast<const bf16x8*>(qp);
    qa[f][1] = *reinterpret_cast<const bf16x8*>(qp + 32);
  }

  floatx4 o[2][4] = {};   // O^T C-layout per frag: d = dt*16 + grp*4 + r, q = q0+f*16+l16
  float l[2] = {0.f, 0.f};

  auto stage = [&](int buf, int k0) {
    const ushort_t* kg = &kr[hb + (size_t)k0 * 64];
#pragma unroll
    for (int i = 0; i < 2; i++) {
      const int j = w * 2 + i;
      gl2lds16(kg + j * 512 + lane * 8, &sK[buf][j * 512]);
    }
#pragma unroll
    for (int i = 0; i < 2; i++) {
      const int d = w * 16 + i * 8;
      gl2lds16(&vt[((size_t)bh * 64 + d + (lane >> 3)) * 2048 + k0 + (lane & 7) * 8],
               &sV[buf][d * 64]);
    }
  };

  stage(0, 0);
  const int g0 = (grp ^ sw) * 8;
  for (int it = 0; it < 32; it++) {
    const int cur = it & 1;
    __syncthreads();                       // drains staging (vmcnt) + read/write fences
    if (it + 1 < 32) stage(1 - cur, (it + 1) * 64);
    const ushort_t* kb = &sK[cur][0];
    const ushort_t* vb = &sV[cur][0];
    // S^T: lane holds key = nt*16 + grp*4 + r, qrow = q0 + f*16 + l16
    floatx4 s[2][4];
#pragma unroll
    for (int nt = 0; nt < 4; nt++) {
      const ushort_t* kp = kb + (nt * 16 + l16) * 64;
      bf16x8 kf0 = *reinterpret_cast<const bf16x8*>(kp + g0);
      bf16x8 kf1 = *reinterpret_cast<const bf16x8*>(kp + (g0 ^ 32));
#pragma unroll
      for (int f = 0; f < 2; f++) {
        floatx4 acc = {};
        acc = __builtin_amdgcn_mfma_f32_16x16x32_bf16(kf0, qa[f][0], acc, 0, 0, 0);
        acc = __builtin_amdgcn_mfma_f32_16x16x32_bf16(kf1, qa[f][1], acc, 0, 0, 0);
        s[f][nt] = acc;
      }
    }
    // softmax (no max) + pack P into B-frags: key = 32c + 16*(j>>2) + grp*4 + (j&3) at k=grp*8+j
    union { ushort_t u[8]; bf16x8 v; } pf[2][2];
#pragma unroll
    for (int f = 0; f < 2; f++) {
      float p[4][4];
      float rs = 0.f;
#pragma unroll
      for (int nt = 0; nt < 4; nt++)
#pragma unroll
        for (int r = 0; r < 4; r++) {
          float pv = __builtin_amdgcn_exp2f(s[f][nt][r]);
          p[nt][r] = pv;
          rs += pv;
        }
      l[f] += rs;
#pragma unroll
      for (int c = 0; c < 2; c++)
#pragma unroll
        for (int j = 0; j < 4; j++) {
          pf[f][c].u[j]     = f2bf_rn(p[2 * c][j]);
          pf[f][c].u[j + 4] = f2bf_rn(p[2 * c + 1][j]);
        }
    }
    // PV: one b128 V-frag per (c,dt), reused across both Q-frags
#pragma unroll
    for (int c = 0; c < 2; c++) {
#pragma unroll
      for (int dt = 0; dt < 4; dt++) {
        const bf16x8 vv = *reinterpret_cast<const bf16x8*>(
            vb + (dt * 16 + l16) * 64 + (((c * 4 + grp) ^ sw) << 3));
#pragma unroll
        for (int f = 0; f < 2; f++)
          o[f][dt] = __builtin_amdgcn_mfma_f32_16x16x32_bf16(vv, pf[f][c].v, o[f][dt], 0, 0, 0);
      }
    }
  }
  // epilogue: reduce l across the 4 key-quarter lanes, scale, store bf16
  const int b = bh >> 4, h = bh & 15;
#pragma unroll
  for (int f = 0; f < 2; f++) {
    float lt = l[f] + __shfl_xor(l[f], 16);
    lt += __shfl_xor(lt, 32);
    const float rl = 1.0f / lt;
    const size_t orow = (size_t)(b * 2048 + q0 + f * 16 + l16) * 1024 + h * 64;
#pragma unroll
    for (int dt = 0; dt < 4; dt++) {
      ushort4v ov;
#pragma unroll
      for (int r = 0; r < 4; r++) ov[r] = f2bf(o[f][dt][r] * rl);
      *reinterpret_cast<ushort4v*>(&aout[orow + dt * 16 + grp * 4]) = ov;
    }
  }
}

extern "C" void kernel_launch(void* const* d_in, const int* in_sizes, int n_in,
                              void* d_out, int out_size, void* d_ws, size_t ws_size,
                              hipStream_t stream) {
  const float* x      = (const float*)d_in[0];   // [2,2048,1024]
  const float* pos    = (const float*)d_in[1];   // [2048,32]
  const float* qkv_w  = (const float*)d_in[2];   // [3072,1024]
  const float* q_nw   = (const float*)d_in[3];   // [64]
  const float* k_nw   = (const float*)d_in[4];   // [64]
  const float* proj_w = (const float*)d_in[5];   // [1024,1024]
  const float* proj_b = (const float*)d_in[6];   // [1024]
  float* out = (float*)d_out;                    // [2,2048,1024] fp32

  ushort_t* x_b     = (ushort_t*)d_ws;                         // 4096*1024
  ushort_t* qkvw_b  = x_b     + (size_t)4096 * 1024;           // 3072*1024
  ushort_t* projw_b = qkvw_b  + (size_t)3072 * 1024;           // 1024*1024
  ushort_t* qkv_b   = projw_b + (size_t)1024 * 1024;           // 4096*3072
  ushort_t* q_r     = qkv_b   + (size_t)4096 * 3072;           // 32*2048*64
  ushort_t* k_r     = q_r     + (size_t)32 * 2048 * 64;
  ushort_t* v_t     = k_r     + (size_t)32 * 2048 * 64;
  ushort_t* a_out   = v_t     + (size_t)32 * 2048 * 64;        // 4096*1024

  cast_f2b<<<4096 * 1024 / 4 / 256, 256, 0, stream>>>(x, x_b, 4096 * 1024);
  cast_f2b<<<3072 * 1024 / 4 / 256, 256, 0, stream>>>(qkv_w, qkvw_b, 3072 * 1024);
  cast_f2b<<<1024 * 1024 / 4 / 256, 256, 0, stream>>>(proj_w, projw_b, 1024 * 1024);

  gemm_bt<true><<<dim3(3072 / 128, 4096 / 128), 256, 0, stream>>>(
      x_b, qkvw_b, (void*)qkv_b, nullptr, 4096, 3072, 1024);

  qkv_post<<<(2 * 16 * 2048) / 4, 256, 0, stream>>>(qkv_b, pos, q_nw, k_nw, q_r, k_r, v_t);

  flash_attn<<<dim3(2048 / 128, 32), 256, 0, stream>>>(q_r, k_r, v_t, a_out);

  gemm_bt<false><<<dim3(1024 / 128, 4096 / 128), 256, 0, stream>>>(
      a_out, projw_b, (void*)out, proj_b, 4096, 1024, 1024);
}

// Round 6
// 233.600 us; speedup vs baseline: 2.2246x; 1.0016x over previous
//
#include <hip/hip_runtime.h>
#include <hip/hip_bf16.h>

typedef unsigned short ushort_t;
using floatx4 = __attribute__((__ext_vector_type__(4))) float;
using bf16x8  = __attribute__((__ext_vector_type__(8))) __bf16;
using ushort4v = __attribute__((__ext_vector_type__(4))) ushort_t;

__device__ __forceinline__ ushort_t f2bf(float f) {
  unsigned int u = __builtin_bit_cast(unsigned int, f);
  u += 0x7FFFu + ((u >> 16) & 1u);   // RNE
  return (ushort_t)(u >> 16);
}
__device__ __forceinline__ float b2f(ushort_t h) {
  unsigned int u = ((unsigned int)h) << 16;
  return __builtin_bit_cast(float, u);
}
// packed f32x2 -> bf16x2 (v_cvt_pk_bf16_f32); memcpy because __hip_bfloat162
// is not trivially copyable (bit_cast rejected it in round 5)
__device__ __forceinline__ unsigned int pkbf(float a, float b) {
  __hip_bfloat162 h = __float22bfloat162_rn(make_float2(a, b));
  unsigned int u;
  __builtin_memcpy(&u, &h, 4);
  return u;
}

// async global->LDS, 16B per lane; lds dest is wave-uniform base (HW adds lane*16)
__device__ __forceinline__ void gl2lds16(const ushort_t* g, ushort_t* l) {
  __builtin_amdgcn_global_load_lds(
      (const __attribute__((address_space(1))) unsigned int*)g,
      (__attribute__((address_space(3))) unsigned int*)l, 16, 0, 0);
}

// ---------------- merged cast fp32 -> bf16 of x, qkv_w, proj_w ----------------
__global__ void cast_all(const float* __restrict__ x, const float* __restrict__ qw,
                         const float* __restrict__ pw, ushort_t* __restrict__ ob) {
  const int T1 = 4096 * 1024, T2 = T1 + 3072 * 1024, T3 = T2 + 1024 * 1024;
  int i = (blockIdx.x * blockDim.x + threadIdx.x) * 4;
  if (i >= T3) return;
  const float* src = (i < T1) ? (x + i) : (i < T2) ? (qw + (i - T1)) : (pw + (i - T2));
  float4 v = *reinterpret_cast<const float4*>(src);
  uint2 o = make_uint2(pkbf(v.x, v.y), pkbf(v.z, v.w));
  *reinterpret_cast<uint2*>(&ob[i]) = o;
}

// ---------------- QKV GEMM + fused RMSNorm/rotary/relayout epilogue ----------------
// C[4096,3072] = x_b[4096,1024] @ qkv_w_b[3072,1024]^T, never materialized:
// each 128-col block is entirely in the q/k/v region; each wave's 64-col half is one head.
// Outputs (bf16): qr [bh][n][d] (q pre-scaled by 0.125*log2e), kr XOR-swizzled,
// vt [bh][d][key] permuted+swizzled.
__global__ __launch_bounds__(256)
void gemm_qkv_fused(const ushort_t* __restrict__ A, const ushort_t* __restrict__ B,
                    const float* __restrict__ pos,
                    const float* __restrict__ qnw, const float* __restrict__ knw,
                    ushort_t* __restrict__ qr, ushort_t* __restrict__ kr,
                    ushort_t* __restrict__ vt) {
  const int K = 1024;
  __shared__ ushort_t sA[128 * 32];
  __shared__ ushort_t sB[128 * 32];
  const int m0 = blockIdx.y * 128, n0 = blockIdx.x * 128;
  const int tid = threadIdx.x;
  const int lane = tid & 63, w = tid >> 6;
  const int wm = (w >> 1) * 64;
  const int grp = lane >> 4, l16 = lane & 15;
  const int r0 = lane >> 2, c0 = (lane & 3) * 8;
  floatx4 acc[4][4] = {};
  for (int k0 = 0; k0 < K; k0 += 32) {
    __syncthreads();
#pragma unroll
    for (int i = 0; i < 2; i++) {
      const int j = w * 2 + i;
      gl2lds16(&A[(size_t)(m0 + j * 16 + r0) * K + k0 + c0], &sA[j * 512]);
      gl2lds16(&B[(size_t)(n0 + j * 16 + r0) * K + k0 + c0], &sB[j * 512]);
    }
    __syncthreads();
    bf16x8 af[4], bfr[4];
#pragma unroll
    for (int i = 0; i < 4; i++)
      af[i] = *reinterpret_cast<const bf16x8*>(&sA[(wm + i * 16 + l16) * 32 + grp * 8]);
#pragma unroll
    for (int i = 0; i < 4; i++)
      bfr[i] = *reinterpret_cast<const bf16x8*>(&sB[((w & 1) * 64 + i * 16 + l16) * 32 + grp * 8]);
#pragma unroll
    for (int i = 0; i < 4; i++)
#pragma unroll
      for (int j = 0; j < 4; j++)
        acc[i][j] = __builtin_amdgcn_mfma_f32_16x16x32_bf16(af[i], bfr[j], acc[i][j], 0, 0, 0);
  }
  // ---- fused epilogue ----
  const int region = n0 >> 10;                       // 0=q,1=k,2=v
  const int h = ((n0 & 1023) >> 6) + (w & 1);        // head this wave owns
  if (region < 2) {
    const float* nwp = (region == 0) ? qnw : knw;
    float wgt[4];
#pragma unroll
    for (int j = 0; j < 4; j++) wgt[j] = nwp[j * 16 + l16];
    const float qmul = (region == 0) ? 0.125f * 1.44269504088896340736f : 1.0f;
#pragma unroll
    for (int i = 0; i < 4; i++) {
#pragma unroll
      for (int rr = 0; rr < 4; rr++) {
        const int t = m0 + wm + i * 16 + grp * 4 + rr;      // token row in [0,4096)
        const int b = t >> 11, n = t & 2047;
        float val[4];
        float s = 0.f;
#pragma unroll
        for (int j = 0; j < 4; j++) { val[j] = acc[i][j][rr]; s += val[j] * val[j]; }
        s += __shfl_xor(s, 1); s += __shfl_xor(s, 2);
        s += __shfl_xor(s, 4); s += __shfl_xor(s, 8);
        const float rn = rsqrtf(s * (1.0f / 64.0f) + 1e-6f);
        const size_t rowbase = ((size_t)(b * 16 + h) * 2048 + n) * 64;
#pragma unroll
        for (int j = 0; j < 4; j++) {
          const float sv = val[j] * rn * wgt[j];
          const float pv = __shfl_xor(sv, 1);
          const float ang = pos[n * 32 + j * 8 + (l16 >> 1)];
          const float cc = __cosf(ang), ss = __sinf(ang);
          const float sgn = (l16 & 1) ? ss : -ss;
          const float outv = (sv * cc + pv * sgn) * qmul;
          const int d = j * 16 + l16;
          if (region == 0) {
            qr[rowbase + d] = f2bf(outv);
          } else {
            const int kpos = ((d >> 3) ^ (n & 7)) * 8 + (d & 7);
            kr[rowbase + kpos] = f2bf(outv);
          }
        }
      }
    }
  } else {
#pragma unroll
    for (int i = 0; i < 4; i++) {
#pragma unroll
      for (int rr = 0; rr < 4; rr++) {
        const int t = m0 + wm + i * 16 + grp * 4 + rr;
        const int b = t >> 11, n = t & 2047;
        const int nw_ = n & 63;
        const int idx = ((nw_ >> 5) << 5) + (((nw_ >> 2) & 3) << 3) +
                        (((nw_ >> 4) & 1) << 2) + (nw_ & 3);
#pragma unroll
        for (int j = 0; j < 4; j++) {
          const int d = j * 16 + l16;
          const int vpos = (((idx >> 3) ^ (d & 7)) << 3) + (idx & 7);
          vt[((size_t)((b * 16 + h) * 64 + d)) * 2048 + (n & ~63) + vpos] = f2bf(acc[i][j][rr]);
        }
      }
    }
  }
}

// ---------------- Flash attention: 2 Q-frags/wave, LDS K/V shared, dbuf ----------------
// No running max: ||q||=||k||=8 after RMSNorm => |score*log2e*scale| <= 11.6, exp2-safe.
__global__ __launch_bounds__(256)
void flash_attn(const ushort_t* __restrict__ qr, const ushort_t* __restrict__ kr,
                const ushort_t* __restrict__ vt, ushort_t* __restrict__ aout) {
  const int bh = blockIdx.y;
  const int w = threadIdx.x >> 6, lane = threadIdx.x & 63;
  const int grp = lane >> 4, l16 = lane & 15;
  const int sw = l16 & 7;
  const int q0 = blockIdx.x * 128 + w * 32;
  const size_t hb = (size_t)bh * 2048 * 64;

  __shared__ ushort_t sK[2][64 * 64];   // [key][d-swizzled]
  __shared__ ushort_t sV[2][64 * 64];   // [d][key permuted+swizzled]

  bf16x8 qa[2][2];
#pragma unroll
  for (int f = 0; f < 2; f++) {
    const ushort_t* qp = &qr[hb + (size_t)(q0 + f * 16 + l16) * 64 + grp * 8];
    qa[f][0] = *reinterpret_cast<const bf16x8*>(qp);
    qa[f][1] = *reinterpret_cast<const bf16x8*>(qp + 32);
  }

  floatx4 o[2][4] = {};
  float l[2] = {0.f, 0.f};

  auto stage = [&](int buf, int k0) {
    const ushort_t* kg = &kr[hb + (size_t)k0 * 64];
#pragma unroll
    for (int i = 0; i < 2; i++) {
      const int j = w * 2 + i;
      gl2lds16(kg + j * 512 + lane * 8, &sK[buf][j * 512]);
    }
#pragma unroll
    for (int i = 0; i < 2; i++) {
      const int d = w * 16 + i * 8;
      gl2lds16(&vt[((size_t)bh * 64 + d + (lane >> 3)) * 2048 + k0 + (lane & 7) * 8],
               &sV[buf][d * 64]);
    }
  };

  stage(0, 0);
  const int g0 = (grp ^ sw) * 8;
  for (int it = 0; it < 32; it++) {
    const int cur = it & 1;
    __syncthreads();
    if (it + 1 < 32) stage(1 - cur, (it + 1) * 64);
    const ushort_t* kb = &sK[cur][0];
    const ushort_t* vb = &sV[cur][0];
    floatx4 s[2][4];
#pragma unroll
    for (int nt = 0; nt < 4; nt++) {
      const ushort_t* kp = kb + (nt * 16 + l16) * 64;
      bf16x8 kf0 = *reinterpret_cast<const bf16x8*>(kp + g0);
      bf16x8 kf1 = *reinterpret_cast<const bf16x8*>(kp + (g0 ^ 32));
#pragma unroll
      for (int f = 0; f < 2; f++) {
        floatx4 acc = {};
        acc = __builtin_amdgcn_mfma_f32_16x16x32_bf16(kf0, qa[f][0], acc, 0, 0, 0);
        acc = __builtin_amdgcn_mfma_f32_16x16x32_bf16(kf1, qa[f][1], acc, 0, 0, 0);
        s[f][nt] = acc;
      }
    }
    union { unsigned int u32[4]; bf16x8 v; } pf[2][2];
#pragma unroll
    for (int f = 0; f < 2; f++) {
      float p[4][4];
      float rs = 0.f;
#pragma unroll
      for (int nt = 0; nt < 4; nt++)
#pragma unroll
        for (int r = 0; r < 4; r++) {
          float pv = __builtin_amdgcn_exp2f(s[f][nt][r]);
          p[nt][r] = pv;
          rs += pv;
        }
      l[f] += rs;
#pragma unroll
      for (int c = 0; c < 2; c++) {
        pf[f][c].u32[0] = pkbf(p[2 * c][0], p[2 * c][1]);
        pf[f][c].u32[1] = pkbf(p[2 * c][2], p[2 * c][3]);
        pf[f][c].u32[2] = pkbf(p[2 * c + 1][0], p[2 * c + 1][1]);
        pf[f][c].u32[3] = pkbf(p[2 * c + 1][2], p[2 * c + 1][3]);
      }
    }
#pragma unroll
    for (int c = 0; c < 2; c++) {
#pragma unroll
      for (int dt = 0; dt < 4; dt++) {
        const bf16x8 vv = *reinterpret_cast<const bf16x8*>(
            vb + (dt * 16 + l16) * 64 + (((c * 4 + grp) ^ sw) << 3));
#pragma unroll
        for (int f = 0; f < 2; f++)
          o[f][dt] = __builtin_amdgcn_mfma_f32_16x16x32_bf16(vv, pf[f][c].v, o[f][dt], 0, 0, 0);
      }
    }
  }
  const int b = bh >> 4, h = bh & 15;
#pragma unroll
  for (int f = 0; f < 2; f++) {
    float lt = l[f] + __shfl_xor(l[f], 16);
    lt += __shfl_xor(lt, 32);
    const float rl = 1.0f / lt;
    const size_t orow = (size_t)(b * 2048 + q0 + f * 16 + l16) * 1024 + h * 64;
#pragma unroll
    for (int dt = 0; dt < 4; dt++) {
      uint2 ov = make_uint2(pkbf(o[f][dt][0] * rl, o[f][dt][1] * rl),
                            pkbf(o[f][dt][2] * rl, o[f][dt][3] * rl));
      *reinterpret_cast<uint2*>(&aout[orow + dt * 16 + grp * 4]) = ov;
    }
  }
}

// ---------------- proj GEMM: out[4096,1024] = a_out @ proj_w^T + b (fp32 out) ----------------
// 128x64 tile (512 blocks = 2/CU), 4 waves of 64x32.
__global__ __launch_bounds__(256)
void gemm_proj(const ushort_t* __restrict__ A, const ushort_t* __restrict__ B,
               float* __restrict__ Cout, const float* __restrict__ bias) {
  const int K = 1024, N = 1024;
  __shared__ ushort_t sA[128 * 32];
  __shared__ ushort_t sB[64 * 32];
  const int m0 = blockIdx.y * 128, n0 = blockIdx.x * 64;
  const int tid = threadIdx.x;
  const int lane = tid & 63, w = tid >> 6;
  const int wm = (w >> 1) * 64, wn = (w & 1) * 32;
  const int grp = lane >> 4, l16 = lane & 15;
  const int r0 = lane >> 2, c0 = (lane & 3) * 8;
  floatx4 acc[4][2] = {};
  for (int k0 = 0; k0 < K; k0 += 32) {
    __syncthreads();
#pragma unroll
    for (int i = 0; i < 2; i++) {
      const int j = w * 2 + i;
      gl2lds16(&A[(size_t)(m0 + j * 16 + r0) * K + k0 + c0], &sA[j * 512]);
    }
    gl2lds16(&B[(size_t)(n0 + w * 16 + r0) * K + k0 + c0], &sB[w * 512]);
    __syncthreads();
    bf16x8 af[4], bfr[2];
#pragma unroll
    for (int i = 0; i < 4; i++)
      af[i] = *reinterpret_cast<const bf16x8*>(&sA[(wm + i * 16 + l16) * 32 + grp * 8]);
#pragma unroll
    for (int j = 0; j < 2; j++)
      bfr[j] = *reinterpret_cast<const bf16x8*>(&sB[(wn + j * 16 + l16) * 32 + grp * 8]);
#pragma unroll
    for (int i = 0; i < 4; i++)
#pragma unroll
      for (int j = 0; j < 2; j++)
        acc[i][j] = __builtin_amdgcn_mfma_f32_16x16x32_bf16(af[i], bfr[j], acc[i][j], 0, 0, 0);
  }
#pragma unroll
  for (int i = 0; i < 4; i++) {
    const int mb = m0 + wm + i * 16 + grp * 4;
#pragma unroll
    for (int j = 0; j < 2; j++) {
      const int nc = n0 + wn + j * 16 + l16;
      const float bv = bias[nc];
#pragma unroll
      for (int rr = 0; rr < 4; rr++)
        Cout[(size_t)(mb + rr) * N + nc] = acc[i][j][rr] + bv;
    }
  }
}

extern "C" void kernel_launch(void* const* d_in, const int* in_sizes, int n_in,
                              void* d_out, int out_size, void* d_ws, size_t ws_size,
                              hipStream_t stream) {
  const float* x      = (const float*)d_in[0];   // [2,2048,1024]
  const float* pos    = (const float*)d_in[1];   // [2048,32]
  const float* qkv_w  = (const float*)d_in[2];   // [3072,1024]
  const float* q_nw   = (const float*)d_in[3];   // [64]
  const float* k_nw   = (const float*)d_in[4];   // [64]
  const float* proj_w = (const float*)d_in[5];   // [1024,1024]
  const float* proj_b = (const float*)d_in[6];   // [1024]
  float* out = (float*)d_out;                    // [2,2048,1024] fp32

  ushort_t* x_b     = (ushort_t*)d_ws;                         // 4096*1024
  ushort_t* qkvw_b  = x_b     + (size_t)4096 * 1024;           // 3072*1024
  ushort_t* projw_b = qkvw_b  + (size_t)3072 * 1024;           // 1024*1024
  ushort_t* q_r     = projw_b + (size_t)1024 * 1024;           // 32*2048*64
  ushort_t* k_r     = q_r     + (size_t)32 * 2048 * 64;
  ushort_t* v_t     = k_r     + (size_t)32 * 2048 * 64;
  ushort_t* a_out   = v_t     + (size_t)32 * 2048 * 64;        // 4096*1024

  // one merged cast kernel: x, qkv_w, proj_w are contiguous in ws
  cast_all<<<8388608 / 4 / 256, 256, 0, stream>>>(x, qkv_w, proj_w, x_b);

  // QKV GEMM with fused RMSNorm+rotary+relayout epilogue
  gemm_qkv_fused<<<dim3(3072 / 128, 4096 / 128), 256, 0, stream>>>(
      x_b, qkvw_b, pos, q_nw, k_nw, q_r, k_r, v_t);

  flash_attn<<<dim3(2048 / 128, 32), 256, 0, stream>>>(q_r, k_r, v_t, a_out);

  gemm_proj<<<dim3(1024 / 64, 4096 / 128), 256, 0, stream>>>(a_out, projw_b, out, proj_b);
}

// Round 7
// 217.560 us; speedup vs baseline: 2.3886x; 1.0737x over previous
//
#include <hip/hip_runtime.h>
#include <hip/hip_bf16.h>

typedef unsigned short ushort_t;
using floatx4 = __attribute__((__ext_vector_type__(4))) float;
using bf16x8  = __attribute__((__ext_vector_type__(8))) __bf16;
using ushort4v = __attribute__((__ext_vector_type__(4))) ushort_t;

__device__ __forceinline__ ushort_t f2bf(float f) {
  unsigned int u = __builtin_bit_cast(unsigned int, f);
  u += 0x7FFFu + ((u >> 16) & 1u);   // RNE
  return (ushort_t)(u >> 16);
}
__device__ __forceinline__ float b2f(ushort_t h) {
  unsigned int u = ((unsigned int)h) << 16;
  return __builtin_bit_cast(float, u);
}
// packed f32x2 -> bf16x2 (v_cvt_pk_bf16_f32); memcpy because __hip_bfloat162
// is not trivially copyable
__device__ __forceinline__ unsigned int pkbf(float a, float b) {
  __hip_bfloat162 h = __float22bfloat162_rn(make_float2(a, b));
  unsigned int u;
  __builtin_memcpy(&u, &h, 4);
  return u;
}

// async global->LDS, 16B per lane; lds dest is wave-uniform base (HW adds lane*16)
__device__ __forceinline__ void gl2lds16(const ushort_t* g, ushort_t* l) {
  __builtin_amdgcn_global_load_lds(
      (const __attribute__((address_space(1))) unsigned int*)g,
      (__attribute__((address_space(3))) unsigned int*)l, 16, 0, 0);
}

// ---------------- merged cast fp32 -> bf16 of x, qkv_w, proj_w ----------------
__global__ void cast_all(const float* __restrict__ x, const float* __restrict__ qw,
                         const float* __restrict__ pw, ushort_t* __restrict__ ob) {
  const int T1 = 4096 * 1024, T2 = T1 + 3072 * 1024, T3 = T2 + 1024 * 1024;
  int i = (blockIdx.x * blockDim.x + threadIdx.x) * 4;
  if (i >= T3) return;
  const float* src = (i < T1) ? (x + i) : (i < T2) ? (qw + (i - T1)) : (pw + (i - T2));
  float4 v = *reinterpret_cast<const float4*>(src);
  uint2 o = make_uint2(pkbf(v.x, v.y), pkbf(v.z, v.w));
  *reinterpret_cast<uint2*>(&ob[i]) = o;
}

// ---------------- QKV GEMM + fused RMSNorm/rotary/relayout epilogue (v2) ----------------
// Epilogue now goes through a per-wave LDS tile so all global I/O is 16B coalesced.
__global__ __launch_bounds__(256)
void gemm_qkv_fused(const ushort_t* __restrict__ A, const ushort_t* __restrict__ B,
                    const float* __restrict__ pos,
                    const float* __restrict__ qnw, const float* __restrict__ knw,
                    ushort_t* __restrict__ qr, ushort_t* __restrict__ kr,
                    ushort_t* __restrict__ vt) {
  const int K = 1024;
  __shared__ ushort_t sA[128 * 32];
  __shared__ ushort_t sB[128 * 32];
  __shared__ __align__(16) ushort_t sE[4][4096];   // 8KB per-wave epilogue tile
  const int m0 = blockIdx.y * 128, n0 = blockIdx.x * 128;
  const int tid = threadIdx.x;
  const int lane = tid & 63, w = tid >> 6;
  const int wm = (w >> 1) * 64;
  const int grp = lane >> 4, l16 = lane & 15;
  const int r0 = lane >> 2, c0 = (lane & 3) * 8;
  floatx4 acc[4][4] = {};
  for (int k0 = 0; k0 < K; k0 += 32) {
    __syncthreads();
#pragma unroll
    for (int i = 0; i < 2; i++) {
      const int j = w * 2 + i;
      gl2lds16(&A[(size_t)(m0 + j * 16 + r0) * K + k0 + c0], &sA[j * 512]);
      gl2lds16(&B[(size_t)(n0 + j * 16 + r0) * K + k0 + c0], &sB[j * 512]);
    }
    __syncthreads();
    bf16x8 af[4], bfr[4];
#pragma unroll
    for (int i = 0; i < 4; i++)
      af[i] = *reinterpret_cast<const bf16x8*>(&sA[(wm + i * 16 + l16) * 32 + grp * 8]);
#pragma unroll
    for (int i = 0; i < 4; i++)
      bfr[i] = *reinterpret_cast<const bf16x8*>(&sB[((w & 1) * 64 + i * 16 + l16) * 32 + grp * 8]);
#pragma unroll
    for (int i = 0; i < 4; i++)
#pragma unroll
      for (int j = 0; j < 4; j++)
        acc[i][j] = __builtin_amdgcn_mfma_f32_16x16x32_bf16(af[i], bfr[j], acc[i][j], 0, 0, 0);
  }
  // ---- fused epilogue v2 ----
  const int region = n0 >> 10;                 // 0=q,1=k,2=v
  const int h = ((n0 & 1023) >> 6) + (w & 1);  // head this wave owns
  const int tbase = m0 + wm;                   // first global token of this wave's tile
  const int bb = tbase >> 11;                  // batch (uniform over tile)
  const int nwin = tbase & 2047;               // 64-aligned token window base
  const int q = lane & 7;                      // phase-B chunk id
  const int lr = lane >> 3;                    // phase-B row-in-group

  if (region < 2) {
    float* sEf = (float*)&sE[w][0];            // 32 tokens x 64 dims fp32 (8KB)
    const float* nwp = (region == 0) ? qnw : knw;
    const float qmul = (region == 0) ? 0.125f * 1.44269504088896340736f : 1.0f;
    float wgt[8];
    *(float4*)&wgt[0] = *(const float4*)&nwp[q * 8];
    *(float4*)&wgt[4] = *(const float4*)&nwp[q * 8 + 4];
#pragma unroll
    for (int hf = 0; hf < 2; hf++) {
      __syncthreads();
      // phase A: dump fp32 [t2][d] with 16B-chunk XOR swizzle by t2&15
#pragma unroll
      for (int i2 = 0; i2 < 2; i2++)
#pragma unroll
        for (int rr = 0; rr < 4; rr++) {
          const int t2 = i2 * 16 + grp * 4 + rr;
#pragma unroll
          for (int j = 0; j < 4; j++) {
            const int cd = (j * 4 + (l16 >> 2)) ^ (t2 & 15);
            sEf[t2 * 64 + cd * 4 + (l16 & 3)] = acc[hf * 2 + i2][j][rr];
          }
        }
      __syncthreads();
      // phase B: 8 lanes per token; lane handles dims [8q, 8q+8)
#pragma unroll
      for (int tg = 0; tg < 4; tg++) {
        const int t2 = tg * 8 + lr;
        const int n = (tbase + hf * 32 + t2) & 2047;
        float v0[8];
        const int ck1 = (2 * q) ^ (t2 & 15), ck2 = (2 * q + 1) ^ (t2 & 15);
        *(float4*)&v0[0] = *(const float4*)&sEf[t2 * 64 + ck1 * 4];
        *(float4*)&v0[4] = *(const float4*)&sEf[t2 * 64 + ck2 * 4];
        float ss = 0.f;
#pragma unroll
        for (int e = 0; e < 8; e++) ss += v0[e] * v0[e];
        ss += __shfl_xor(ss, 1); ss += __shfl_xor(ss, 2); ss += __shfl_xor(ss, 4);
        const float rn = rsqrtf(ss * (1.0f / 64.0f) + 1e-6f);
        float4 ang = *(const float4*)&pos[n * 32 + q * 4];
        union { unsigned int u32[4]; uint4 v4; } ov;
#pragma unroll
        for (int p = 0; p < 4; p++) {
          const float a = ((const float*)&ang)[p];
          const float cc = __cosf(a), sn = __sinf(a);
          const float xr = v0[2 * p] * rn * wgt[2 * p];
          const float xi = v0[2 * p + 1] * rn * wgt[2 * p + 1];
          ov.u32[p] = pkbf((xr * cc - xi * sn) * qmul, (xr * sn + xi * cc) * qmul);
        }
        const size_t rowb = ((size_t)(bb * 16 + h) * 2048 + n) * 64;
        if (region == 0)
          *reinterpret_cast<uint4*>(&qr[rowb + q * 8]) = ov.v4;
        else
          *reinterpret_cast<uint4*>(&kr[rowb + (q ^ (n & 7)) * 8]) = ov.v4;
      }
    }
  } else {
    // v region: LDS [d][t] bf16, rr-quads packed as b64; 8B-chunk swizzle by d&15
    __syncthreads();
#pragma unroll
    for (int i = 0; i < 4; i++)
#pragma unroll
      for (int j = 0; j < 4; j++) {
        const int d = j * 16 + l16;
        const int ct = (i * 4 + grp) ^ (d & 15);
        uint2 pk = make_uint2(pkbf(acc[i][j][0], acc[i][j][1]),
                              pkbf(acc[i][j][2], acc[i][j][3]));
        *reinterpret_cast<uint2*>(&sE[w][d * 64 + ct * 4]) = pk;
      }
    __syncthreads();
    // each lane emits one permuted 16B chunk per d-row group
#pragma unroll
    for (int dd = 0; dd < 8; dd++) {
      const int d = dd * 8 + lr;
      const int cta = 8 * (q >> 2) + (q & 3);        // token-run chunks (t1, t1+16)
      union { ushort4v h[2]; uint4 v4; } ob;
      ob.h[0] = *reinterpret_cast<const ushort4v*>(&sE[w][d * 64 + ((cta ^ (d & 15)) * 4)]);
      ob.h[1] = *reinterpret_cast<const ushort4v*>(&sE[w][d * 64 + (((cta + 4) ^ (d & 15)) * 4)]);
      *reinterpret_cast<uint4*>(
          &vt[((size_t)(bb * 16 + h) * 64 + d) * 2048 + nwin + (q ^ (d & 7)) * 8]) = ob.v4;
    }
  }
}

// ---------------- Flash attention: 2 Q-frags/wave, LDS K/V shared, dbuf ----------------
// No running max: ||q||=||k||=8 after RMSNorm => |score*log2e*scale| <= 11.6, exp2-safe.
__global__ __launch_bounds__(256)
void flash_attn(const ushort_t* __restrict__ qr, const ushort_t* __restrict__ kr,
                const ushort_t* __restrict__ vt, ushort_t* __restrict__ aout) {
  const int bh = blockIdx.y;
  const int w = threadIdx.x >> 6, lane = threadIdx.x & 63;
  const int grp = lane >> 4, l16 = lane & 15;
  const int sw = l16 & 7;
  const int q0 = blockIdx.x * 128 + w * 32;
  const size_t hb = (size_t)bh * 2048 * 64;

  __shared__ ushort_t sK[2][64 * 64];   // [key][d-swizzled]
  __shared__ ushort_t sV[2][64 * 64];   // [d][key permuted+swizzled]

  bf16x8 qa[2][2];
#pragma unroll
  for (int f = 0; f < 2; f++) {
    const ushort_t* qp = &qr[hb + (size_t)(q0 + f * 16 + l16) * 64 + grp * 8];
    qa[f][0] = *reinterpret_cast<const bf16x8*>(qp);
    qa[f][1] = *reinterpret_cast<const bf16x8*>(qp + 32);
  }

  floatx4 o[2][4] = {};
  float l[2] = {0.f, 0.f};

  auto stage = [&](int buf, int k0) {
    const ushort_t* kg = &kr[hb + (size_t)k0 * 64];
#pragma unroll
    for (int i = 0; i < 2; i++) {
      const int j = w * 2 + i;
      gl2lds16(kg + j * 512 + lane * 8, &sK[buf][j * 512]);
    }
#pragma unroll
    for (int i = 0; i < 2; i++) {
      const int d = w * 16 + i * 8;
      gl2lds16(&vt[((size_t)bh * 64 + d + (lane >> 3)) * 2048 + k0 + (lane & 7) * 8],
               &sV[buf][d * 64]);
    }
  };

  stage(0, 0);
  const int g0 = (grp ^ sw) * 8;
  for (int it = 0; it < 32; it++) {
    const int cur = it & 1;
    __syncthreads();
    if (it + 1 < 32) stage(1 - cur, (it + 1) * 64);
    const ushort_t* kb = &sK[cur][0];
    const ushort_t* vb = &sV[cur][0];
    floatx4 s[2][4];
#pragma unroll
    for (int nt = 0; nt < 4; nt++) {
      const ushort_t* kp = kb + (nt * 16 + l16) * 64;
      bf16x8 kf0 = *reinterpret_cast<const bf16x8*>(kp + g0);
      bf16x8 kf1 = *reinterpret_cast<const bf16x8*>(kp + (g0 ^ 32));
#pragma unroll
      for (int f = 0; f < 2; f++) {
        floatx4 acc = {};
        acc = __builtin_amdgcn_mfma_f32_16x16x32_bf16(kf0, qa[f][0], acc, 0, 0, 0);
        acc = __builtin_amdgcn_mfma_f32_16x16x32_bf16(kf1, qa[f][1], acc, 0, 0, 0);
        s[f][nt] = acc;
      }
    }
    union { unsigned int u32[4]; bf16x8 v; } pf[2][2];
#pragma unroll
    for (int f = 0; f < 2; f++) {
      float p[4][4];
      float rs = 0.f;
#pragma unroll
      for (int nt = 0; nt < 4; nt++)
#pragma unroll
        for (int r = 0; r < 4; r++) {
          float pv = __builtin_amdgcn_exp2f(s[f][nt][r]);
          p[nt][r] = pv;
          rs += pv;
        }
      l[f] += rs;
#pragma unroll
      for (int c = 0; c < 2; c++) {
        pf[f][c].u32[0] = pkbf(p[2 * c][0], p[2 * c][1]);
        pf[f][c].u32[1] = pkbf(p[2 * c][2], p[2 * c][3]);
        pf[f][c].u32[2] = pkbf(p[2 * c + 1][0], p[2 * c + 1][1]);
        pf[f][c].u32[3] = pkbf(p[2 * c + 1][2], p[2 * c + 1][3]);
      }
    }
#pragma unroll
    for (int c = 0; c < 2; c++) {
#pragma unroll
      for (int dt = 0; dt < 4; dt++) {
        const bf16x8 vv = *reinterpret_cast<const bf16x8*>(
            vb + (dt * 16 + l16) * 64 + (((c * 4 + grp) ^ sw) << 3));
#pragma unroll
        for (int f = 0; f < 2; f++)
          o[f][dt] = __builtin_amdgcn_mfma_f32_16x16x32_bf16(vv, pf[f][c].v, o[f][dt], 0, 0, 0);
      }
    }
  }
  const int b = bh >> 4, h = bh & 15;
#pragma unroll
  for (int f = 0; f < 2; f++) {
    float lt = l[f] + __shfl_xor(l[f], 16);
    lt += __shfl_xor(lt, 32);
    const float rl = 1.0f / lt;
    const size_t orow = (size_t)(b * 2048 + q0 + f * 16 + l16) * 1024 + h * 64;
#pragma unroll
    for (int dt = 0; dt < 4; dt++) {
      uint2 ov = make_uint2(pkbf(o[f][dt][0] * rl, o[f][dt][1] * rl),
                            pkbf(o[f][dt][2] * rl, o[f][dt][3] * rl));
      *reinterpret_cast<uint2*>(&aout[orow + dt * 16 + grp * 4]) = ov;
    }
  }
}

// ---------------- proj GEMM: out[4096,1024] = a_out @ proj_w^T + b (fp32 out) ----------------
// 128x64 tile (512 blocks = 2/CU), 4 waves of 64x32.
__global__ __launch_bounds__(256)
void gemm_proj(const ushort_t* __restrict__ A, const ushort_t* __restrict__ B,
               float* __restrict__ Cout, const float* __restrict__ bias) {
  const int K = 1024, N = 1024;
  __shared__ ushort_t sA[128 * 32];
  __shared__ ushort_t sB[64 * 32];
  const int m0 = blockIdx.y * 128, n0 = blockIdx.x * 64;
  const int tid = threadIdx.x;
  const int lane = tid & 63, w = tid >> 6;
  const int wm = (w >> 1) * 64, wn = (w & 1) * 32;
  const int grp = lane >> 4, l16 = lane & 15;
  const int r0 = lane >> 2, c0 = (lane & 3) * 8;
  floatx4 acc[4][2] = {};
  for (int k0 = 0; k0 < K; k0 += 32) {
    __syncthreads();
#pragma unroll
    for (int i = 0; i < 2; i++) {
      const int j = w * 2 + i;
      gl2lds16(&A[(size_t)(m0 + j * 16 + r0) * K + k0 + c0], &sA[j * 512]);
    }
    gl2lds16(&B[(size_t)(n0 + w * 16 + r0) * K + k0 + c0], &sB[w * 512]);
    __syncthreads();
    bf16x8 af[4], bfr[2];
#pragma unroll
    for (int i = 0; i < 4; i++)
      af[i] = *reinterpret_cast<const bf16x8*>(&sA[(wm + i * 16 + l16) * 32 + grp * 8]);
#pragma unroll
    for (int j = 0; j < 2; j++)
      bfr[j] = *reinterpret_cast<const bf16x8*>(&sB[(wn + j * 16 + l16) * 32 + grp * 8]);
#pragma unroll
    for (int i = 0; i < 4; i++)
#pragma unroll
      for (int j = 0; j < 2; j++)
        acc[i][j] = __builtin_amdgcn_mfma_f32_16x16x32_bf16(af[i], bfr[j], acc[i][j], 0, 0, 0);
  }
#pragma unroll
  for (int i = 0; i < 4; i++) {
    const int mb = m0 + wm + i * 16 + grp * 4;
#pragma unroll
    for (int j = 0; j < 2; j++) {
      const int nc = n0 + wn + j * 16 + l16;
      const float bv = bias[nc];
#pragma unroll
      for (int rr = 0; rr < 4; rr++)
        Cout[(size_t)(mb + rr) * N + nc] = acc[i][j][rr] + bv;
    }
  }
}

extern "C" void kernel_launch(void* const* d_in, const int* in_sizes, int n_in,
                              void* d_out, int out_size, void* d_ws, size_t ws_size,
                              hipStream_t stream) {
  const float* x      = (const float*)d_in[0];   // [2,2048,1024]
  const float* pos    = (const float*)d_in[1];   // [2048,32]
  const float* qkv_w  = (const float*)d_in[2];   // [3072,1024]
  const float* q_nw   = (const float*)d_in[3];   // [64]
  const float* k_nw   = (const float*)d_in[4];   // [64]
  const float* proj_w = (const float*)d_in[5];   // [1024,1024]
  const float* proj_b = (const float*)d_in[6];   // [1024]
  float* out = (float*)d_out;                    // [2,2048,1024] fp32

  ushort_t* x_b     = (ushort_t*)d_ws;                         // 4096*1024
  ushort_t* qkvw_b  = x_b     + (size_t)4096 * 1024;           // 3072*1024
  ushort_t* projw_b = qkvw_b  + (size_t)3072 * 1024;           // 1024*1024
  ushort_t* q_r     = projw_b + (size_t)1024 * 1024;           // 32*2048*64
  ushort_t* k_r     = q_r     + (size_t)32 * 2048 * 64;
  ushort_t* v_t     = k_r     + (size_t)32 * 2048 * 64;
  ushort_t* a_out   = v_t     + (size_t)32 * 2048 * 64;        // 4096*1024

  cast_all<<<8388608 / 4 / 256, 256, 0, stream>>>(x, qkv_w, proj_w, x_b);

  gemm_qkv_fused<<<dim3(3072 / 128, 4096 / 128), 256, 0, stream>>>(
      x_b, qkvw_b, pos, q_nw, k_nw, q_r, k_r, v_t);

  flash_attn<<<dim3(2048 / 128, 32), 256, 0, stream>>>(q_r, k_r, v_t, a_out);

  gemm_proj<<<dim3(1024 / 64, 4096 / 128), 256, 0, stream>>>(a_out, projw_b, out, proj_b);
}

// Round 8
// 214.317 us; speedup vs baseline: 2.4248x; 1.0151x over previous
//
#include <hip/hip_runtime.h>
#include <hip/hip_bf16.h>

typedef unsigned short ushort_t;
using floatx4 = __attribute__((__ext_vector_type__(4))) float;
using bf16x8  = __attribute__((__ext_vector_type__(8))) __bf16;
using ushort4v = __attribute__((__ext_vector_type__(4))) ushort_t;

// packed f32x2 -> bf16x2 (v_cvt_pk_bf16_f32); memcpy because __hip_bfloat162
// is not trivially copyable
__device__ __forceinline__ unsigned int pkbf(float a, float b) {
  __hip_bfloat162 h = __float22bfloat162_rn(make_float2(a, b));
  unsigned int u;
  __builtin_memcpy(&u, &h, 4);
  return u;
}

// async global->LDS, 16B per lane; lds dest is wave-uniform base (HW adds lane*16)
__device__ __forceinline__ void gl2lds16(const ushort_t* g, ushort_t* l) {
  __builtin_amdgcn_global_load_lds(
      (const __attribute__((address_space(1))) unsigned int*)g,
      (__attribute__((address_space(3))) unsigned int*)l, 16, 0, 0);
}

// ---------------- merged cast fp32 -> bf16 of x, qkv_w, proj_w + cos/sin table ----------------
__global__ void cast_all(const float* __restrict__ x, const float* __restrict__ qw,
                         const float* __restrict__ pw, ushort_t* __restrict__ ob,
                         const float* __restrict__ pos, float* __restrict__ cs) {
  const int T1 = 4096 * 1024, T2 = T1 + 3072 * 1024, T3 = T2 + 1024 * 1024;
  const int tid = blockIdx.x * blockDim.x + threadIdx.x;
  if (tid < 65536) {              // 2048 tokens x 32 angles
    const float a = pos[tid];
    cs[2 * tid]     = __cosf(a);
    cs[2 * tid + 1] = __sinf(a);
  }
  const int i = tid * 4;
  if (i < T3) {
    const float* src = (i < T1) ? (x + i) : (i < T2) ? (qw + (i - T1)) : (pw + (i - T2));
    float4 v = *reinterpret_cast<const float4*>(src);
    uint2 o = make_uint2(pkbf(v.x, v.y), pkbf(v.z, v.w));
    *reinterpret_cast<uint2*>(&ob[i]) = o;
  }
}

// ---------------- QKV GEMM + fused RMSNorm/rotary/relayout epilogue ----------------
// Epilogue via per-wave LDS tile; all global I/O 16B coalesced; cos/sin from table.
__global__ __launch_bounds__(256)
void gemm_qkv_fused(const ushort_t* __restrict__ A, const ushort_t* __restrict__ B,
                    const float* __restrict__ cs,
                    const float* __restrict__ qnw, const float* __restrict__ knw,
                    ushort_t* __restrict__ qr, ushort_t* __restrict__ kr,
                    ushort_t* __restrict__ vt) {
  const int K = 1024;
  __shared__ ushort_t sA[128 * 32];
  __shared__ ushort_t sB[128 * 32];
  __shared__ __align__(16) ushort_t sE[4][4096];   // 8KB per-wave epilogue tile
  const int m0 = blockIdx.y * 128, n0 = blockIdx.x * 128;
  const int tid = threadIdx.x;
  const int lane = tid & 63, w = tid >> 6;
  const int wm = (w >> 1) * 64;
  const int grp = lane >> 4, l16 = lane & 15;
  const int r0 = lane >> 2, c0 = (lane & 3) * 8;
  floatx4 acc[4][4] = {};
  for (int k0 = 0; k0 < K; k0 += 32) {
    __syncthreads();
#pragma unroll
    for (int i = 0; i < 2; i++) {
      const int j = w * 2 + i;
      gl2lds16(&A[(size_t)(m0 + j * 16 + r0) * K + k0 + c0], &sA[j * 512]);
      gl2lds16(&B[(size_t)(n0 + j * 16 + r0) * K + k0 + c0], &sB[j * 512]);
    }
    __syncthreads();
    bf16x8 af[4], bfr[4];
#pragma unroll
    for (int i = 0; i < 4; i++)
      af[i] = *reinterpret_cast<const bf16x8*>(&sA[(wm + i * 16 + l16) * 32 + grp * 8]);
#pragma unroll
    for (int i = 0; i < 4; i++)
      bfr[i] = *reinterpret_cast<const bf16x8*>(&sB[((w & 1) * 64 + i * 16 + l16) * 32 + grp * 8]);
#pragma unroll
    for (int i = 0; i < 4; i++)
#pragma unroll
      for (int j = 0; j < 4; j++)
        acc[i][j] = __builtin_amdgcn_mfma_f32_16x16x32_bf16(af[i], bfr[j], acc[i][j], 0, 0, 0);
  }
  // ---- fused epilogue ----
  const int region = n0 >> 10;                 // 0=q,1=k,2=v
  const int h = ((n0 & 1023) >> 6) + (w & 1);  // head this wave owns
  const int tbase = m0 + wm;                   // first global token of this wave's tile
  const int bb = tbase >> 11;
  const int nwin = tbase & 2047;
  const int q = lane & 7;
  const int lr = lane >> 3;

  if (region < 2) {
    float* sEf = (float*)&sE[w][0];            // 32 tokens x 64 dims fp32 (8KB)
    const float* nwp = (region == 0) ? qnw : knw;
    const float qmul = (region == 0) ? 0.125f * 1.44269504088896340736f : 1.0f;
    float wgt[8];
    *(float4*)&wgt[0] = *(const float4*)&nwp[q * 8];
    *(float4*)&wgt[4] = *(const float4*)&nwp[q * 8 + 4];
#pragma unroll
    for (int hf = 0; hf < 2; hf++) {
      __syncthreads();
      // phase A: dump fp32 [t2][d] with 16B-chunk XOR swizzle by t2&15
#pragma unroll
      for (int i2 = 0; i2 < 2; i2++)
#pragma unroll
        for (int rr = 0; rr < 4; rr++) {
          const int t2 = i2 * 16 + grp * 4 + rr;
#pragma unroll
          for (int j = 0; j < 4; j++) {
            const int cd = (j * 4 + (l16 >> 2)) ^ (t2 & 15);
            sEf[t2 * 64 + cd * 4 + (l16 & 3)] = acc[hf * 2 + i2][j][rr];
          }
        }
      __syncthreads();
      // phase B: 8 lanes per token; lane handles dims [8q, 8q+8)
#pragma unroll
      for (int tg = 0; tg < 4; tg++) {
        const int t2 = tg * 8 + lr;
        const int n = (tbase + hf * 32 + t2) & 2047;
        float v0[8];
        const int ck1 = (2 * q) ^ (t2 & 15), ck2 = (2 * q + 1) ^ (t2 & 15);
        *(float4*)&v0[0] = *(const float4*)&sEf[t2 * 64 + ck1 * 4];
        *(float4*)&v0[4] = *(const float4*)&sEf[t2 * 64 + ck2 * 4];
        float ss = 0.f;
#pragma unroll
        for (int e = 0; e < 8; e++) ss += v0[e] * v0[e];
        ss += __shfl_xor(ss, 1); ss += __shfl_xor(ss, 2); ss += __shfl_xor(ss, 4);
        const float rn = rsqrtf(ss * (1.0f / 64.0f) + 1e-6f);
        // cos/sin from table: 4 pairs at angles q*4..q*4+3
        float4 c01 = *(const float4*)&cs[(n * 32 + q * 4) * 2];
        float4 c23 = *(const float4*)&cs[(n * 32 + q * 4) * 2 + 4];
        float ccv[4] = {c01.x, c01.z, c23.x, c23.z};
        float snv[4] = {c01.y, c01.w, c23.y, c23.w};
        union { unsigned int u32[4]; uint4 v4; } ov;
#pragma unroll
        for (int p = 0; p < 4; p++) {
          const float cc = ccv[p], sn = snv[p];
          const float xr = v0[2 * p] * rn * wgt[2 * p];
          const float xi = v0[2 * p + 1] * rn * wgt[2 * p + 1];
          ov.u32[p] = pkbf((xr * cc - xi * sn) * qmul, (xr * sn + xi * cc) * qmul);
        }
        const size_t rowb = ((size_t)(bb * 16 + h) * 2048 + n) * 64;
        if (region == 0)
          *reinterpret_cast<uint4*>(&qr[rowb + q * 8]) = ov.v4;
        else
          *reinterpret_cast<uint4*>(&kr[rowb + (q ^ (n & 7)) * 8]) = ov.v4;
      }
    }
  } else {
    // v region: LDS [d][t] bf16, rr-quads packed as b64; 8B-chunk swizzle by d&15
    __syncthreads();
#pragma unroll
    for (int i = 0; i < 4; i++)
#pragma unroll
      for (int j = 0; j < 4; j++) {
        const int d = j * 16 + l16;
        const int ct = (i * 4 + grp) ^ (d & 15);
        uint2 pk = make_uint2(pkbf(acc[i][j][0], acc[i][j][1]),
                              pkbf(acc[i][j][2], acc[i][j][3]));
        *reinterpret_cast<uint2*>(&sE[w][d * 64 + ct * 4]) = pk;
      }
    __syncthreads();
#pragma unroll
    for (int dd = 0; dd < 8; dd++) {
      const int d = dd * 8 + lr;
      const int cta = 8 * (q >> 2) + (q & 3);        // token-run chunks (t1, t1+16)
      union { ushort4v h[2]; uint4 v4; } ob;
      ob.h[0] = *reinterpret_cast<const ushort4v*>(&sE[w][d * 64 + ((cta ^ (d & 15)) * 4)]);
      ob.h[1] = *reinterpret_cast<const ushort4v*>(&sE[w][d * 64 + (((cta + 4) ^ (d & 15)) * 4)]);
      *reinterpret_cast<uint4*>(
          &vt[((size_t)(bb * 16 + h) * 64 + d) * 2048 + nwin + (q ^ (d & 7)) * 8]) = ob.v4;
    }
  }
}

// ---------------- Flash attention v5: 128-key tiles (half the barriers), ones-MFMA l ----------
// No running max: ||q||=||k||=8 after RMSNorm => |score*log2e*scale| <= 11.6, exp2-safe.
// Denominator l computed by mfma(ones, P) on the matrix pipe (all 4 C-regs = full chunk sum).
__global__ __launch_bounds__(256)
void flash_attn(const ushort_t* __restrict__ qr, const ushort_t* __restrict__ kr,
                const ushort_t* __restrict__ vt, ushort_t* __restrict__ aout) {
  const int bh = blockIdx.y;
  const int w = threadIdx.x >> 6, lane = threadIdx.x & 63;
  const int grp = lane >> 4, l16 = lane & 15;
  const int sw = l16 & 7;
  const int q0 = blockIdx.x * 128 + w * 32;
  const size_t hb = (size_t)bh * 2048 * 64;

  __shared__ ushort_t sK[2][128 * 64];   // [key][d-swizzled], 16KB each
  __shared__ ushort_t sV[2][64 * 128];   // [d][128-key window permuted+swizzled], 16KB each

  bf16x8 qa[2][2];
#pragma unroll
  for (int f = 0; f < 2; f++) {
    const ushort_t* qp = &qr[hb + (size_t)(q0 + f * 16 + l16) * 64 + grp * 8];
    qa[f][0] = *reinterpret_cast<const bf16x8*>(qp);
    qa[f][1] = *reinterpret_cast<const bf16x8*>(qp + 32);
  }

  floatx4 o[2][4] = {};
  floatx4 ol[2] = {};     // ones-row accumulator: every reg = Sigma p for this lane's q

  union { ushort_t u[8]; bf16x8 v; } onef;
#pragma unroll
  for (int e = 0; e < 8; e++) onef.u[e] = 0x3F80;   // bf16 1.0

  auto stage = [&](int buf, int k0) {
    const ushort_t* kg = &kr[hb + (size_t)k0 * 64];
#pragma unroll
    for (int i = 0; i < 4; i++) {
      const int j = w * 4 + i;
      gl2lds16(kg + j * 512 + lane * 8, &sK[buf][j * 512]);
    }
#pragma unroll
    for (int i = 0; i < 4; i++) {
      const int d = w * 16 + i * 4;
      gl2lds16(&vt[((size_t)bh * 64 + d + (lane >> 4)) * 2048 + k0 + (lane & 15) * 8],
               &sV[buf][d * 128]);
    }
  };

  stage(0, 0);
  const int g0 = (grp ^ sw) * 8;
  for (int it = 0; it < 16; it++) {
    const int cur = it & 1;
    __syncthreads();
    if (it + 1 < 16) stage(1 - cur, (it + 1) * 128);
#pragma unroll
    for (int hh = 0; hh < 2; hh++) {
      const ushort_t* kb = &sK[cur][hh * 64 * 64];
      const ushort_t* vb = &sV[cur][hh * 64];
      floatx4 s[2][4];
#pragma unroll
      for (int nt = 0; nt < 4; nt++) {
        const ushort_t* kp = kb + (nt * 16 + l16) * 64;
        bf16x8 kf0 = *reinterpret_cast<const bf16x8*>(kp + g0);
        bf16x8 kf1 = *reinterpret_cast<const bf16x8*>(kp + (g0 ^ 32));
#pragma unroll
        for (int f = 0; f < 2; f++) {
          floatx4 acc = {};
          acc = __builtin_amdgcn_mfma_f32_16x16x32_bf16(kf0, qa[f][0], acc, 0, 0, 0);
          acc = __builtin_amdgcn_mfma_f32_16x16x32_bf16(kf1, qa[f][1], acc, 0, 0, 0);
          s[f][nt] = acc;
        }
      }
      union { unsigned int u32[4]; bf16x8 v; } pf[2][2];
#pragma unroll
      for (int f = 0; f < 2; f++) {
        float p[4][4];
#pragma unroll
        for (int nt = 0; nt < 4; nt++)
#pragma unroll
          for (int r = 0; r < 4; r++)
            p[nt][r] = __builtin_amdgcn_exp2f(s[f][nt][r]);
#pragma unroll
        for (int c = 0; c < 2; c++) {
          pf[f][c].u32[0] = pkbf(p[2 * c][0], p[2 * c][1]);
          pf[f][c].u32[1] = pkbf(p[2 * c][2], p[2 * c][3]);
          pf[f][c].u32[2] = pkbf(p[2 * c + 1][0], p[2 * c + 1][1]);
          pf[f][c].u32[3] = pkbf(p[2 * c + 1][2], p[2 * c + 1][3]);
        }
      }
#pragma unroll
      for (int c = 0; c < 2; c++) {
#pragma unroll
        for (int f = 0; f < 2; f++)
          ol[f] = __builtin_amdgcn_mfma_f32_16x16x32_bf16(onef.v, pf[f][c].v, ol[f], 0, 0, 0);
#pragma unroll
        for (int dt = 0; dt < 4; dt++) {
          const bf16x8 vv = *reinterpret_cast<const bf16x8*>(
              vb + (dt * 16 + l16) * 128 + (((c * 4 + grp) ^ sw) << 3));
#pragma unroll
          for (int f = 0; f < 2; f++)
            o[f][dt] = __builtin_amdgcn_mfma_f32_16x16x32_bf16(vv, pf[f][c].v, o[f][dt], 0, 0, 0);
        }
      }
    }
  }
  const int b = bh >> 4, h = bh & 15;
#pragma unroll
  for (int f = 0; f < 2; f++) {
    const float rl = 1.0f / ol[f][0];
    const size_t orow = (size_t)(b * 2048 + q0 + f * 16 + l16) * 1024 + h * 64;
#pragma unroll
    for (int dt = 0; dt < 4; dt++) {
      uint2 ov = make_uint2(pkbf(o[f][dt][0] * rl, o[f][dt][1] * rl),
                            pkbf(o[f][dt][2] * rl, o[f][dt][3] * rl));
      *reinterpret_cast<uint2*>(&aout[orow + dt * 16 + grp * 4]) = ov;
    }
  }
}

// ---------------- proj GEMM: out[4096,1024] = a_out @ proj_w^T + b (fp32 out) ----------------
// 128x64 tile (512 blocks = 2/CU); epilogue via per-wave LDS transpose -> dwordx4 stores.
__global__ __launch_bounds__(256)
void gemm_proj(const ushort_t* __restrict__ A, const ushort_t* __restrict__ B,
               float* __restrict__ Cout, const float* __restrict__ bias) {
  const int K = 1024, N = 1024;
  __shared__ ushort_t sA[128 * 32];
  __shared__ ushort_t sB[64 * 32];
  __shared__ float sT[4][2048];     // per-wave 64 rows x 32 cols fp32 (8KB)
  const int m0 = blockIdx.y * 128, n0 = blockIdx.x * 64;
  const int tid = threadIdx.x;
  const int lane = tid & 63, w = tid >> 6;
  const int wm = (w >> 1) * 64, wn = (w & 1) * 32;
  const int grp = lane >> 4, l16 = lane & 15;
  const int r0 = lane >> 2, c0 = (lane & 3) * 8;
  floatx4 acc[4][2] = {};
  for (int k0 = 0; k0 < K; k0 += 32) {
    __syncthreads();
#pragma unroll
    for (int i = 0; i < 2; i++) {
      const int j = w * 2 + i;
      gl2lds16(&A[(size_t)(m0 + j * 16 + r0) * K + k0 + c0], &sA[j * 512]);
    }
    gl2lds16(&B[(size_t)(n0 + w * 16 + r0) * K + k0 + c0], &sB[w * 512]);
    __syncthreads();
    bf16x8 af[4], bfr[2];
#pragma unroll
    for (int i = 0; i < 4; i++)
      af[i] = *reinterpret_cast<const bf16x8*>(&sA[(wm + i * 16 + l16) * 32 + grp * 8]);
#pragma unroll
    for (int j = 0; j < 2; j++)
      bfr[j] = *reinterpret_cast<const bf16x8*>(&sB[(wn + j * 16 + l16) * 32 + grp * 8]);
#pragma unroll
    for (int i = 0; i < 4; i++)
#pragma unroll
      for (int j = 0; j < 2; j++)
        acc[i][j] = __builtin_amdgcn_mfma_f32_16x16x32_bf16(af[i], bfr[j], acc[i][j], 0, 0, 0);
  }
  // phase A: bias + store to per-wave LDS tile, 4B-chunk swizzle by row&7
  float bv[2];
#pragma unroll
  for (int j = 0; j < 2; j++) bv[j] = bias[n0 + wn + j * 16 + l16];
#pragma unroll
  for (int i = 0; i < 4; i++)
#pragma unroll
    for (int j = 0; j < 2; j++) {
      const int col = j * 16 + l16, c4 = col >> 2;
#pragma unroll
      for (int rr = 0; rr < 4; rr++) {
        const int row = i * 16 + grp * 4 + rr;
        sT[w][row * 32 + ((c4 ^ (row & 7)) << 2) + (col & 3)] = acc[i][j][rr] + bv[j];
      }
    }
  __builtin_amdgcn_s_waitcnt(0);   // per-wave tile: LDS writes before reads (lgkmcnt)
  // phase B: lane (lr,ch) stores rows rg*8+lr, cols ch*4..ch*4+3 as dwordx4
  const int lr = lane >> 3, ch = lane & 7;
#pragma unroll
  for (int rg = 0; rg < 8; rg++) {
    const int row = rg * 8 + lr;
    float4 vvv = *(const float4*)&sT[w][row * 32 + ((ch ^ (row & 7)) << 2)];
    *reinterpret_cast<float4*>(&Cout[(size_t)(m0 + wm + row) * N + n0 + wn + ch * 4]) = vvv;
  }
}

extern "C" void kernel_launch(void* const* d_in, const int* in_sizes, int n_in,
                              void* d_out, int out_size, void* d_ws, size_t ws_size,
                              hipStream_t stream) {
  const float* x      = (const float*)d_in[0];   // [2,2048,1024]
  const float* pos    = (const float*)d_in[1];   // [2048,32]
  const float* qkv_w  = (const float*)d_in[2];   // [3072,1024]
  const float* q_nw   = (const float*)d_in[3];   // [64]
  const float* k_nw   = (const float*)d_in[4];   // [64]
  const float* proj_w = (const float*)d_in[5];   // [1024,1024]
  const float* proj_b = (const float*)d_in[6];   // [1024]
  float* out = (float*)d_out;                    // [2,2048,1024] fp32

  ushort_t* x_b     = (ushort_t*)d_ws;                         // 4096*1024
  ushort_t* qkvw_b  = x_b     + (size_t)4096 * 1024;           // 3072*1024
  ushort_t* projw_b = qkvw_b  + (size_t)3072 * 1024;           // 1024*1024
  ushort_t* q_r     = projw_b + (size_t)1024 * 1024;           // 32*2048*64
  ushort_t* k_r     = q_r     + (size_t)32 * 2048 * 64;
  ushort_t* v_t     = k_r     + (size_t)32 * 2048 * 64;
  ushort_t* a_out   = v_t     + (size_t)32 * 2048 * 64;        // 4096*1024
  float*    cs_tab  = (float*)(a_out + (size_t)4096 * 1024);   // 65536*2 fp32 (512KB)

  cast_all<<<8388608 / 4 / 256, 256, 0, stream>>>(x, qkv_w, proj_w, x_b, pos, cs_tab);

  gemm_qkv_fused<<<dim3(3072 / 128, 4096 / 128), 256, 0, stream>>>(
      x_b, qkvw_b, cs_tab, q_nw, k_nw, q_r, k_r, v_t);

  flash_attn<<<dim3(2048 / 128, 32), 256, 0, stream>>>(q_r, k_r, v_t, a_out);

  gemm_proj<<<dim3(1024 / 64, 4096 / 128), 256, 0, stream>>>(a_out, projw_b, out, proj_b);
}

// Round 9
// 201.006 us; speedup vs baseline: 2.5854x; 1.0662x over previous
//
#include <hip/hip_runtime.h>
#include <hip/hip_bf16.h>

typedef unsigned short ushort_t;
using floatx4 = __attribute__((__ext_vector_type__(4))) float;
using bf16x8  = __attribute__((__ext_vector_type__(8))) __bf16;
using ushort4v = __attribute__((__ext_vector_type__(4))) ushort_t;

// packed f32x2 -> bf16x2 (v_cvt_pk_bf16_f32); memcpy because __hip_bfloat162
// is not trivially copyable
__device__ __forceinline__ unsigned int pkbf(float a, float b) {
  __hip_bfloat162 h = __float22bfloat162_rn(make_float2(a, b));
  unsigned int u;
  __builtin_memcpy(&u, &h, 4);
  return u;
}

// async global->LDS, 16B per lane; lds dest is wave-uniform base (HW adds lane*16)
__device__ __forceinline__ void gl2lds16(const ushort_t* g, ushort_t* l) {
  __builtin_amdgcn_global_load_lds(
      (const __attribute__((address_space(1))) unsigned int*)g,
      (__attribute__((address_space(3))) unsigned int*)l, 16, 0, 0);
}

// ---------------- merged cast fp32 -> bf16 of x, qkv_w, proj_w + cos/sin table ----------------
__global__ void cast_all(const float* __restrict__ x, const float* __restrict__ qw,
                         const float* __restrict__ pw, ushort_t* __restrict__ ob,
                         const float* __restrict__ pos, float* __restrict__ cs) {
  const int T1 = 4096 * 1024, T2 = T1 + 3072 * 1024, T3 = T2 + 1024 * 1024;
  const int tid = blockIdx.x * blockDim.x + threadIdx.x;
  if (tid < 65536) {              // 2048 tokens x 32 angles
    const float a = pos[tid];
    cs[2 * tid]     = __cosf(a);
    cs[2 * tid + 1] = __sinf(a);
  }
  const int i = tid * 4;
  if (i < T3) {
    const float* src = (i < T1) ? (x + i) : (i < T2) ? (qw + (i - T1)) : (pw + (i - T2));
    float4 v = *reinterpret_cast<const float4*>(src);
    uint2 o = make_uint2(pkbf(v.x, v.y), pkbf(v.z, v.w));
    *reinterpret_cast<uint2*>(&ob[i]) = o;
  }
}

// ---------------- QKV GEMM (BK=64, swizzled LDS) + fused RMSNorm/rotary/relayout ----------------
// LDS tiles [128][64] bf16, chunk c of row r stored at c^(r&7) (16B chunks) so both
// gl2lds staging (lane-linear) and b128 fragment reads are conflict-free.
// Epilogue tile (32KB) aliases sA+sB; per-wave, so only one barrier after the K-loop.
__global__ __launch_bounds__(256)
void gemm_qkv_fused(const ushort_t* __restrict__ A, const ushort_t* __restrict__ B,
                    const float* __restrict__ cs,
                    const float* __restrict__ qnw, const float* __restrict__ knw,
                    ushort_t* __restrict__ qr, ushort_t* __restrict__ kr,
                    ushort_t* __restrict__ vt) {
  const int K = 1024;
  __shared__ __align__(16) ushort_t smem[16384];   // 32KB: sA | sB, aliased by sE
  ushort_t* sA = smem;
  ushort_t* sB = smem + 8192;
  const int m0 = blockIdx.y * 128, n0 = blockIdx.x * 128;
  const int tid = threadIdx.x;
  const int lane = tid & 63, w = tid >> 6;
  const int wm = (w >> 1) * 64;
  const int grp = lane >> 4, l16 = lane & 15;
  const int r8 = lane >> 3;                         // row-in-chunk for staging
  const int c8 = ((lane & 7) ^ r8) * 8;             // swizzled source col (elems)
  floatx4 acc[4][4] = {};
  for (int k0 = 0; k0 < K; k0 += 64) {
    __syncthreads();
#pragma unroll
    for (int i = 0; i < 4; i++) {
      const int j = w * 4 + i;                      // chunk 0..15 (8 rows x 128B)
      gl2lds16(&A[(size_t)(m0 + j * 8 + r8) * K + k0 + c8], &sA[j * 512]);
      gl2lds16(&B[(size_t)(n0 + j * 8 + r8) * K + k0 + c8], &sB[j * 512]);
    }
    __syncthreads();
#pragma unroll
    for (int kk = 0; kk < 2; kk++) {
      bf16x8 af[4], bfr[4];
#pragma unroll
      for (int i = 0; i < 4; i++) {
        const int ra = wm + i * 16 + l16;
        af[i] = *reinterpret_cast<const bf16x8*>(
            &sA[ra * 64 + (((kk * 4 + grp) ^ (ra & 7)) << 3)]);
      }
#pragma unroll
      for (int i = 0; i < 4; i++) {
        const int rb = (w & 1) * 64 + i * 16 + l16;
        bfr[i] = *reinterpret_cast<const bf16x8*>(
            &sB[rb * 64 + (((kk * 4 + grp) ^ (rb & 7)) << 3)]);
      }
#pragma unroll
      for (int i = 0; i < 4; i++)
#pragma unroll
        for (int j = 0; j < 4; j++)
          acc[i][j] = __builtin_amdgcn_mfma_f32_16x16x32_bf16(af[i], bfr[j], acc[i][j], 0, 0, 0);
    }
  }
  __syncthreads();                 // all K-loop LDS reads done before epilogue overwrites
  // ---- fused epilogue (per-wave 8KB tile aliased over sA/sB) ----
  ushort_t* sE = smem + w * 4096;
  const int region = n0 >> 10;                 // 0=q,1=k,2=v
  const int h = ((n0 & 1023) >> 6) + (w & 1);  // head this wave owns
  const int tbase = m0 + wm;
  const int bb = tbase >> 11;
  const int nwin = tbase & 2047;
  const int q = lane & 7;
  const int lr = lane >> 3;

  if (region < 2) {
    float* sEf = (float*)sE;                   // 32 tokens x 64 dims fp32 (8KB)
    const float* nwp = (region == 0) ? qnw : knw;
    const float qmul = (region == 0) ? 0.125f * 1.44269504088896340736f : 1.0f;
    float wgt[8];
    *(float4*)&wgt[0] = *(const float4*)&nwp[q * 8];
    *(float4*)&wgt[4] = *(const float4*)&nwp[q * 8 + 4];
#pragma unroll
    for (int hf = 0; hf < 2; hf++) {
      __builtin_amdgcn_s_waitcnt(0);           // prior per-wave LDS reads complete
      // phase A: dump fp32 [t2][d] with 16B-chunk XOR swizzle by t2&15
#pragma unroll
      for (int i2 = 0; i2 < 2; i2++)
#pragma unroll
        for (int rr = 0; rr < 4; rr++) {
          const int t2 = i2 * 16 + grp * 4 + rr;
#pragma unroll
          for (int j = 0; j < 4; j++) {
            const int cd = (j * 4 + (l16 >> 2)) ^ (t2 & 15);
            sEf[t2 * 64 + cd * 4 + (l16 & 3)] = acc[hf * 2 + i2][j][rr];
          }
        }
      __builtin_amdgcn_s_waitcnt(0);
      // phase B: 8 lanes per token; lane handles dims [8q, 8q+8)
#pragma unroll
      for (int tg = 0; tg < 4; tg++) {
        const int t2 = tg * 8 + lr;
        const int n = (tbase + hf * 32 + t2) & 2047;
        float v0[8];
        const int ck1 = (2 * q) ^ (t2 & 15), ck2 = (2 * q + 1) ^ (t2 & 15);
        *(float4*)&v0[0] = *(const float4*)&sEf[t2 * 64 + ck1 * 4];
        *(float4*)&v0[4] = *(const float4*)&sEf[t2 * 64 + ck2 * 4];
        float ss = 0.f;
#pragma unroll
        for (int e = 0; e < 8; e++) ss += v0[e] * v0[e];
        ss += __shfl_xor(ss, 1); ss += __shfl_xor(ss, 2); ss += __shfl_xor(ss, 4);
        const float rn = rsqrtf(ss * (1.0f / 64.0f) + 1e-6f);
        float4 c01 = *(const float4*)&cs[(n * 32 + q * 4) * 2];
        float4 c23 = *(const float4*)&cs[(n * 32 + q * 4) * 2 + 4];
        float ccv[4] = {c01.x, c01.z, c23.x, c23.z};
        float snv[4] = {c01.y, c01.w, c23.y, c23.w};
        union { unsigned int u32[4]; uint4 v4; } ov;
#pragma unroll
        for (int p = 0; p < 4; p++) {
          const float cc = ccv[p], sn = snv[p];
          const float xr = v0[2 * p] * rn * wgt[2 * p];
          const float xi = v0[2 * p + 1] * rn * wgt[2 * p + 1];
          ov.u32[p] = pkbf((xr * cc - xi * sn) * qmul, (xr * sn + xi * cc) * qmul);
        }
        const size_t rowb = ((size_t)(bb * 16 + h) * 2048 + n) * 64;
        if (region == 0)
          *reinterpret_cast<uint4*>(&qr[rowb + q * 8]) = ov.v4;
        else
          *reinterpret_cast<uint4*>(&kr[rowb + (q ^ (n & 7)) * 8]) = ov.v4;
      }
    }
  } else {
    // v region: LDS [d][t] bf16, rr-quads packed as b64; 8B-chunk swizzle by d&15
#pragma unroll
    for (int i = 0; i < 4; i++)
#pragma unroll
      for (int j = 0; j < 4; j++) {
        const int d = j * 16 + l16;
        const int ct = (i * 4 + grp) ^ (d & 15);
        uint2 pk = make_uint2(pkbf(acc[i][j][0], acc[i][j][1]),
                              pkbf(acc[i][j][2], acc[i][j][3]));
        *reinterpret_cast<uint2*>(&sE[d * 64 + ct * 4]) = pk;
      }
    __builtin_amdgcn_s_waitcnt(0);
#pragma unroll
    for (int dd = 0; dd < 8; dd++) {
      const int d = dd * 8 + lr;
      const int cta = 8 * (q >> 2) + (q & 3);        // token-run chunks (t1, t1+16)
      union { ushort4v hh[2]; uint4 v4; } ob;
      ob.hh[0] = *reinterpret_cast<const ushort4v*>(&sE[d * 64 + ((cta ^ (d & 15)) * 4)]);
      ob.hh[1] = *reinterpret_cast<const ushort4v*>(&sE[d * 64 + (((cta + 4) ^ (d & 15)) * 4)]);
      *reinterpret_cast<uint4*>(
          &vt[((size_t)(bb * 16 + h) * 64 + d) * 2048 + nwin + (q ^ (d & 7)) * 8]) = ob.v4;
    }
  }
}

// ---------------- Flash attention v5: 128-key tiles, ones-MFMA denominator ----------------
// No running max: ||q||=||k||=8 after RMSNorm => |score*log2e*scale| <= 11.6, exp2-safe.
__global__ __launch_bounds__(256)
void flash_attn(const ushort_t* __restrict__ qr, const ushort_t* __restrict__ kr,
                const ushort_t* __restrict__ vt, ushort_t* __restrict__ aout) {
  const int bh = blockIdx.y;
  const int w = threadIdx.x >> 6, lane = threadIdx.x & 63;
  const int grp = lane >> 4, l16 = lane & 15;
  const int sw = l16 & 7;
  const int q0 = blockIdx.x * 128 + w * 32;
  const size_t hb = (size_t)bh * 2048 * 64;

  __shared__ ushort_t sK[2][128 * 64];   // [key][d-swizzled], 16KB each
  __shared__ ushort_t sV[2][64 * 128];   // [d][128-key window permuted+swizzled], 16KB each

  bf16x8 qa[2][2];
#pragma unroll
  for (int f = 0; f < 2; f++) {
    const ushort_t* qp = &qr[hb + (size_t)(q0 + f * 16 + l16) * 64 + grp * 8];
    qa[f][0] = *reinterpret_cast<const bf16x8*>(qp);
    qa[f][1] = *reinterpret_cast<const bf16x8*>(qp + 32);
  }

  floatx4 o[2][4] = {};
  floatx4 ol[2] = {};     // ones-row accumulator: every reg = Sigma p for this lane's q

  union { ushort_t u[8]; bf16x8 v; } onef;
#pragma unroll
  for (int e = 0; e < 8; e++) onef.u[e] = 0x3F80;   // bf16 1.0

  auto stage = [&](int buf, int k0) {
    const ushort_t* kg = &kr[hb + (size_t)k0 * 64];
#pragma unroll
    for (int i = 0; i < 4; i++) {
      const int j = w * 4 + i;
      gl2lds16(kg + j * 512 + lane * 8, &sK[buf][j * 512]);
    }
#pragma unroll
    for (int i = 0; i < 4; i++) {
      const int d = w * 16 + i * 4;
      gl2lds16(&vt[((size_t)bh * 64 + d + (lane >> 4)) * 2048 + k0 + (lane & 15) * 8],
               &sV[buf][d * 128]);
    }
  };

  stage(0, 0);
  const int g0 = (grp ^ sw) * 8;
  for (int it = 0; it < 16; it++) {
    const int cur = it & 1;
    __syncthreads();
    if (it + 1 < 16) stage(1 - cur, (it + 1) * 128);
#pragma unroll
    for (int hh = 0; hh < 2; hh++) {
      const ushort_t* kb = &sK[cur][hh * 64 * 64];
      const ushort_t* vb = &sV[cur][hh * 64];
      floatx4 s[2][4];
#pragma unroll
      for (int nt = 0; nt < 4; nt++) {
        const ushort_t* kp = kb + (nt * 16 + l16) * 64;
        bf16x8 kf0 = *reinterpret_cast<const bf16x8*>(kp + g0);
        bf16x8 kf1 = *reinterpret_cast<const bf16x8*>(kp + (g0 ^ 32));
#pragma unroll
        for (int f = 0; f < 2; f++) {
          floatx4 acc = {};
          acc = __builtin_amdgcn_mfma_f32_16x16x32_bf16(kf0, qa[f][0], acc, 0, 0, 0);
          acc = __builtin_amdgcn_mfma_f32_16x16x32_bf16(kf1, qa[f][1], acc, 0, 0, 0);
          s[f][nt] = acc;
        }
      }
      union { unsigned int u32[4]; bf16x8 v; } pf[2][2];
#pragma unroll
      for (int f = 0; f < 2; f++) {
        float p[4][4];
#pragma unroll
        for (int nt = 0; nt < 4; nt++)
#pragma unroll
          for (int r = 0; r < 4; r++)
            p[nt][r] = __builtin_amdgcn_exp2f(s[f][nt][r]);
#pragma unroll
        for (int c = 0; c < 2; c++) {
          pf[f][c].u32[0] = pkbf(p[2 * c][0], p[2 * c][1]);
          pf[f][c].u32[1] = pkbf(p[2 * c][2], p[2 * c][3]);
          pf[f][c].u32[2] = pkbf(p[2 * c + 1][0], p[2 * c + 1][1]);
          pf[f][c].u32[3] = pkbf(p[2 * c + 1][2], p[2 * c + 1][3]);
        }
      }
#pragma unroll
      for (int c = 0; c < 2; c++) {
#pragma unroll
        for (int f = 0; f < 2; f++)
          ol[f] = __builtin_amdgcn_mfma_f32_16x16x32_bf16(onef.v, pf[f][c].v, ol[f], 0, 0, 0);
#pragma unroll
        for (int dt = 0; dt < 4; dt++) {
          const bf16x8 vv = *reinterpret_cast<const bf16x8*>(
              vb + (dt * 16 + l16) * 128 + (((c * 4 + grp) ^ sw) << 3));
#pragma unroll
          for (int f = 0; f < 2; f++)
            o[f][dt] = __builtin_amdgcn_mfma_f32_16x16x32_bf16(vv, pf[f][c].v, o[f][dt], 0, 0, 0);
        }
      }
    }
  }
  const int b = bh >> 4, h = bh & 15;
#pragma unroll
  for (int f = 0; f < 2; f++) {
    const float rl = 1.0f / ol[f][0];
    const size_t orow = (size_t)(b * 2048 + q0 + f * 16 + l16) * 1024 + h * 64;
#pragma unroll
    for (int dt = 0; dt < 4; dt++) {
      uint2 ov = make_uint2(pkbf(o[f][dt][0] * rl, o[f][dt][1] * rl),
                            pkbf(o[f][dt][2] * rl, o[f][dt][3] * rl));
      *reinterpret_cast<uint2*>(&aout[orow + dt * 16 + grp * 4]) = ov;
    }
  }
}

// ---------------- proj GEMM (BK=64, swizzled): out = a_out @ proj_w^T + b (fp32) ----------------
__global__ __launch_bounds__(256)
void gemm_proj(const ushort_t* __restrict__ A, const ushort_t* __restrict__ B,
               float* __restrict__ Cout, const float* __restrict__ bias) {
  const int K = 1024, N = 1024;
  __shared__ __align__(16) ushort_t sA[8192];   // 128x64
  __shared__ __align__(16) ushort_t sB[4096];   // 64x64
  __shared__ float sT[4][2048];                 // per-wave 64x32 fp32 (8KB each)
  const int m0 = blockIdx.y * 128, n0 = blockIdx.x * 64;
  const int tid = threadIdx.x;
  const int lane = tid & 63, w = tid >> 6;
  const int wm = (w >> 1) * 64, wn = (w & 1) * 32;
  const int grp = lane >> 4, l16 = lane & 15;
  const int r8 = lane >> 3;
  const int c8 = ((lane & 7) ^ r8) * 8;
  floatx4 acc[4][2] = {};
  for (int k0 = 0; k0 < K; k0 += 64) {
    __syncthreads();
#pragma unroll
    for (int i = 0; i < 4; i++) {
      const int j = w * 4 + i;
      gl2lds16(&A[(size_t)(m0 + j * 8 + r8) * K + k0 + c8], &sA[j * 512]);
    }
#pragma unroll
    for (int i = 0; i < 2; i++) {
      const int j = w * 2 + i;
      gl2lds16(&B[(size_t)(n0 + j * 8 + r8) * K + k0 + c8], &sB[j * 512]);
    }
    __syncthreads();
#pragma unroll
    for (int kk = 0; kk < 2; kk++) {
      bf16x8 af[4], bfr[2];
#pragma unroll
      for (int i = 0; i < 4; i++) {
        const int ra = wm + i * 16 + l16;
        af[i] = *reinterpret_cast<const bf16x8*>(
            &sA[ra * 64 + (((kk * 4 + grp) ^ (ra & 7)) << 3)]);
      }
#pragma unroll
      for (int j = 0; j < 2; j++) {
        const int rb = wn + j * 16 + l16;
        bfr[j] = *reinterpret_cast<const bf16x8*>(
            &sB[rb * 64 + (((kk * 4 + grp) ^ (rb & 7)) << 3)]);
      }
#pragma unroll
      for (int i = 0; i < 4; i++)
#pragma unroll
        for (int j = 0; j < 2; j++)
          acc[i][j] = __builtin_amdgcn_mfma_f32_16x16x32_bf16(af[i], bfr[j], acc[i][j], 0, 0, 0);
    }
  }
  // phase A: bias + store to per-wave LDS tile, 4B-chunk swizzle by row&7
  float bv[2];
#pragma unroll
  for (int j = 0; j < 2; j++) bv[j] = bias[n0 + wn + j * 16 + l16];
#pragma unroll
  for (int i = 0; i < 4; i++)
#pragma unroll
    for (int j = 0; j < 2; j++) {
      const int col = j * 16 + l16, c4 = col >> 2;
#pragma unroll
      for (int rr = 0; rr < 4; rr++) {
        const int row = i * 16 + grp * 4 + rr;
        sT[w][row * 32 + ((c4 ^ (row & 7)) << 2) + (col & 3)] = acc[i][j][rr] + bv[j];
      }
    }
  __builtin_amdgcn_s_waitcnt(0);   // per-wave tile: LDS writes before reads
  const int lr = lane >> 3, ch = lane & 7;
#pragma unroll
  for (int rg = 0; rg < 8; rg++) {
    const int row = rg * 8 + lr;
    float4 vvv = *(const float4*)&sT[w][row * 32 + ((ch ^ (row & 7)) << 2)];
    *reinterpret_cast<float4*>(&Cout[(size_t)(m0 + wm + row) * N + n0 + wn + ch * 4]) = vvv;
  }
}

extern "C" void kernel_launch(void* const* d_in, const int* in_sizes, int n_in,
                              void* d_out, int out_size, void* d_ws, size_t ws_size,
                              hipStream_t stream) {
  const float* x      = (const float*)d_in[0];   // [2,2048,1024]
  const float* pos    = (const float*)d_in[1];   // [2048,32]
  const float* qkv_w  = (const float*)d_in[2];   // [3072,1024]
  const float* q_nw   = (const float*)d_in[3];   // [64]
  const float* k_nw   = (const float*)d_in[4];   // [64]
  const float* proj_w = (const float*)d_in[5];   // [1024,1024]
  const float* proj_b = (const float*)d_in[6];   // [1024]
  float* out = (float*)d_out;                    // [2,2048,1024] fp32

  ushort_t* x_b     = (ushort_t*)d_ws;                         // 4096*1024
  ushort_t* qkvw_b  = x_b     + (size_t)4096 * 1024;           // 3072*1024
  ushort_t* projw_b = qkvw_b  + (size_t)3072 * 1024;           // 1024*1024
  ushort_t* q_r     = projw_b + (size_t)1024 * 1024;           // 32*2048*64
  ushort_t* k_r     = q_r     + (size_t)32 * 2048 * 64;
  ushort_t* v_t     = k_r     + (size_t)32 * 2048 * 64;
  ushort_t* a_out   = v_t     + (size_t)32 * 2048 * 64;        // 4096*1024
  float*    cs_tab  = (float*)(a_out + (size_t)4096 * 1024);   // 65536*2 fp32 (512KB)

  cast_all<<<8388608 / 4 / 256, 256, 0, stream>>>(x, qkv_w, proj_w, x_b, pos, cs_tab);

  gemm_qkv_fused<<<dim3(3072 / 128, 4096 / 128), 256, 0, stream>>>(
      x_b, qkvw_b, cs_tab, q_nw, k_nw, q_r, k_r, v_t);

  flash_attn<<<dim3(2048 / 128, 32), 256, 0, stream>>>(q_r, k_r, v_t, a_out);

  gemm_proj<<<dim3(1024 / 64, 4096 / 128), 256, 0, stream>>>(a_out, projw_b, out, proj_b);
}

// Round 10
// 195.949 us; speedup vs baseline: 2.6521x; 1.0258x over previous
//
#include <hip/hip_runtime.h>
#include <hip/hip_bf16.h>

typedef unsigned short ushort_t;
using floatx4 = __attribute__((__ext_vector_type__(4))) float;
using bf16x8  = __attribute__((__ext_vector_type__(8))) __bf16;
using ushort4v = __attribute__((__ext_vector_type__(4))) ushort_t;

// packed f32x2 -> bf16x2 (v_cvt_pk_bf16_f32); memcpy because __hip_bfloat162
// is not trivially copyable
__device__ __forceinline__ unsigned int pkbf(float a, float b) {
  __hip_bfloat162 h = __float22bfloat162_rn(make_float2(a, b));
  unsigned int u;
  __builtin_memcpy(&u, &h, 4);
  return u;
}

// async global->LDS, 16B per lane; lds dest is wave-uniform base (HW adds lane*16)
__device__ __forceinline__ void gl2lds16(const ushort_t* g, ushort_t* l) {
  __builtin_amdgcn_global_load_lds(
      (const __attribute__((address_space(1))) unsigned int*)g,
      (__attribute__((address_space(3))) unsigned int*)l, 16, 0, 0);
}

// ---------------- merged cast fp32 -> bf16 of x, qkv_w, proj_w + cos/sin table ----------------
__global__ void cast_all(const float* __restrict__ x, const float* __restrict__ qw,
                         const float* __restrict__ pw, ushort_t* __restrict__ ob,
                         const float* __restrict__ pos, float* __restrict__ cs) {
  const int T1 = 4096 * 1024, T2 = T1 + 3072 * 1024, T3 = T2 + 1024 * 1024;
  const int tid = blockIdx.x * blockDim.x + threadIdx.x;
  if (tid < 65536) {              // 2048 tokens x 32 angles
    const float a = pos[tid];
    cs[2 * tid]     = __cosf(a);
    cs[2 * tid + 1] = __sinf(a);
  }
  const int i = tid * 4;
  if (i < T3) {
    const float* src = (i < T1) ? (x + i) : (i < T2) ? (qw + (i - T1)) : (pw + (i - T2));
    float4 v = *reinterpret_cast<const float4*>(src);
    uint2 o = make_uint2(pkbf(v.x, v.y), pkbf(v.z, v.w));
    *reinterpret_cast<uint2*>(&ob[i]) = o;
  }
}

// ---------------- QKV GEMM (BK=64, swizzled LDS) + fused RMSNorm/rotary/relayout ----------------
// grid (mtile=x, ntile=y): id%8 = mtile%8 pins 4 A-tiles (1MB) per XCD, reused 24x in L2.
__global__ __launch_bounds__(256)
void gemm_qkv_fused(const ushort_t* __restrict__ A, const ushort_t* __restrict__ B,
                    const float* __restrict__ cs,
                    const float* __restrict__ qnw, const float* __restrict__ knw,
                    ushort_t* __restrict__ qr, ushort_t* __restrict__ kr,
                    ushort_t* __restrict__ vt) {
  const int K = 1024;
  __shared__ __align__(16) ushort_t smem[16384];   // 32KB: sA | sB, aliased by sE
  ushort_t* sA = smem;
  ushort_t* sB = smem + 8192;
  const int m0 = blockIdx.x * 128, n0 = blockIdx.y * 128;   // XCD-pinned m
  const int tid = threadIdx.x;
  const int lane = tid & 63, w = tid >> 6;
  const int wm = (w >> 1) * 64;
  const int grp = lane >> 4, l16 = lane & 15;
  const int r8 = lane >> 3;                         // row-in-chunk for staging
  const int c8 = ((lane & 7) ^ r8) * 8;             // swizzled source col (elems)
  floatx4 acc[4][4] = {};
  for (int k0 = 0; k0 < K; k0 += 64) {
    __syncthreads();
#pragma unroll
    for (int i = 0; i < 4; i++) {
      const int j = w * 4 + i;                      // chunk 0..15 (8 rows x 128B)
      gl2lds16(&A[(size_t)(m0 + j * 8 + r8) * K + k0 + c8], &sA[j * 512]);
      gl2lds16(&B[(size_t)(n0 + j * 8 + r8) * K + k0 + c8], &sB[j * 512]);
    }
    __syncthreads();
#pragma unroll
    for (int kk = 0; kk < 2; kk++) {
      bf16x8 af[4], bfr[4];
#pragma unroll
      for (int i = 0; i < 4; i++) {
        const int ra = wm + i * 16 + l16;
        af[i] = *reinterpret_cast<const bf16x8*>(
            &sA[ra * 64 + (((kk * 4 + grp) ^ (ra & 7)) << 3)]);
      }
#pragma unroll
      for (int i = 0; i < 4; i++) {
        const int rb = (w & 1) * 64 + i * 16 + l16;
        bfr[i] = *reinterpret_cast<const bf16x8*>(
            &sB[rb * 64 + (((kk * 4 + grp) ^ (rb & 7)) << 3)]);
      }
#pragma unroll
      for (int i = 0; i < 4; i++)
#pragma unroll
        for (int j = 0; j < 4; j++)
          acc[i][j] = __builtin_amdgcn_mfma_f32_16x16x32_bf16(af[i], bfr[j], acc[i][j], 0, 0, 0);
    }
  }
  __syncthreads();                 // all K-loop LDS reads done before epilogue overwrites
  // ---- fused epilogue (per-wave 8KB tile aliased over sA/sB) ----
  ushort_t* sE = smem + w * 4096;
  const int region = n0 >> 10;                 // 0=q,1=k,2=v
  const int h = ((n0 & 1023) >> 6) + (w & 1);  // head this wave owns
  const int tbase = m0 + wm;
  const int bb = tbase >> 11;
  const int nwin = tbase & 2047;
  const int q = lane & 7;
  const int lr = lane >> 3;

  if (region < 2) {
    float* sEf = (float*)sE;                   // 32 tokens x 64 dims fp32 (8KB)
    const float* nwp = (region == 0) ? qnw : knw;
    const float qmul = (region == 0) ? 0.125f * 1.44269504088896340736f : 1.0f;
    float wgt[8];
    *(float4*)&wgt[0] = *(const float4*)&nwp[q * 8];
    *(float4*)&wgt[4] = *(const float4*)&nwp[q * 8 + 4];
#pragma unroll
    for (int hf = 0; hf < 2; hf++) {
      __builtin_amdgcn_s_waitcnt(0);           // prior per-wave LDS reads complete
      // phase A: dump fp32 [t2][d] with 16B-chunk XOR swizzle by t2&15
#pragma unroll
      for (int i2 = 0; i2 < 2; i2++)
#pragma unroll
        for (int rr = 0; rr < 4; rr++) {
          const int t2 = i2 * 16 + grp * 4 + rr;
#pragma unroll
          for (int j = 0; j < 4; j++) {
            const int cd = (j * 4 + (l16 >> 2)) ^ (t2 & 15);
            sEf[t2 * 64 + cd * 4 + (l16 & 3)] = acc[hf * 2 + i2][j][rr];
          }
        }
      __builtin_amdgcn_s_waitcnt(0);
      // phase B: 8 lanes per token; lane handles dims [8q, 8q+8)
#pragma unroll
      for (int tg = 0; tg < 4; tg++) {
        const int t2 = tg * 8 + lr;
        const int n = (tbase + hf * 32 + t2) & 2047;
        float v0[8];
        const int ck1 = (2 * q) ^ (t2 & 15), ck2 = (2 * q + 1) ^ (t2 & 15);
        *(float4*)&v0[0] = *(const float4*)&sEf[t2 * 64 + ck1 * 4];
        *(float4*)&v0[4] = *(const float4*)&sEf[t2 * 64 + ck2 * 4];
        float ss = 0.f;
#pragma unroll
        for (int e = 0; e < 8; e++) ss += v0[e] * v0[e];
        ss += __shfl_xor(ss, 1); ss += __shfl_xor(ss, 2); ss += __shfl_xor(ss, 4);
        const float rn = rsqrtf(ss * (1.0f / 64.0f) + 1e-6f);
        float4 c01 = *(const float4*)&cs[(n * 32 + q * 4) * 2];
        float4 c23 = *(const float4*)&cs[(n * 32 + q * 4) * 2 + 4];
        float ccv[4] = {c01.x, c01.z, c23.x, c23.z};
        float snv[4] = {c01.y, c01.w, c23.y, c23.w};
        union { unsigned int u32[4]; uint4 v4; } ov;
#pragma unroll
        for (int p = 0; p < 4; p++) {
          const float cc = ccv[p], sn = snv[p];
          const float xr = v0[2 * p] * rn * wgt[2 * p];
          const float xi = v0[2 * p + 1] * rn * wgt[2 * p + 1];
          ov.u32[p] = pkbf((xr * cc - xi * sn) * qmul, (xr * sn + xi * cc) * qmul);
        }
        const size_t rowb = ((size_t)(bb * 16 + h) * 2048 + n) * 64;
        if (region == 0)
          *reinterpret_cast<uint4*>(&qr[rowb + q * 8]) = ov.v4;
        else
          *reinterpret_cast<uint4*>(&kr[rowb + (q ^ (n & 7)) * 8]) = ov.v4;
      }
    }
  } else {
    // v region: LDS [d][t] bf16, rr-quads packed as b64; 8B-chunk swizzle by d&15
#pragma unroll
    for (int i = 0; i < 4; i++)
#pragma unroll
      for (int j = 0; j < 4; j++) {
        const int d = j * 16 + l16;
        const int ct = (i * 4 + grp) ^ (d & 15);
        uint2 pk = make_uint2(pkbf(acc[i][j][0], acc[i][j][1]),
                              pkbf(acc[i][j][2], acc[i][j][3]));
        *reinterpret_cast<uint2*>(&sE[d * 64 + ct * 4]) = pk;
      }
    __builtin_amdgcn_s_waitcnt(0);
#pragma unroll
    for (int dd = 0; dd < 8; dd++) {
      const int d = dd * 8 + lr;
      const int cta = 8 * (q >> 2) + (q & 3);        // token-run chunks (t1, t1+16)
      union { ushort4v hh[2]; uint4 v4; } ob;
      ob.hh[0] = *reinterpret_cast<const ushort4v*>(&sE[d * 64 + ((cta ^ (d & 15)) * 4)]);
      ob.hh[1] = *reinterpret_cast<const ushort4v*>(&sE[d * 64 + (((cta + 4) ^ (d & 15)) * 4)]);
      *reinterpret_cast<uint4*>(
          &vt[((size_t)(bb * 16 + h) * 64 + d) * 2048 + nwin + (q ^ (d & 7)) * 8]) = ob.v4;
    }
  }
}

// ---------------- Flash attention: 128-key tiles, ones-MFMA denominator ----------------
// grid (bh=x, qtile=y): id%8 = bh%8 pins each head's 16 q-tile blocks to one XCD ->
// K/V staging hits L2 (~256KB active set) instead of L3/HBM (was 3x over-fetch).
__global__ __launch_bounds__(256)
void flash_attn(const ushort_t* __restrict__ qr, const ushort_t* __restrict__ kr,
                const ushort_t* __restrict__ vt, ushort_t* __restrict__ aout) {
  const int bh = blockIdx.x;
  const int w = threadIdx.x >> 6, lane = threadIdx.x & 63;
  const int grp = lane >> 4, l16 = lane & 15;
  const int sw = l16 & 7;
  const int q0 = blockIdx.y * 128 + w * 32;
  const size_t hb = (size_t)bh * 2048 * 64;

  __shared__ ushort_t sK[2][128 * 64];   // [key][d-swizzled], 16KB each
  __shared__ ushort_t sV[2][64 * 128];   // [d][128-key window permuted+swizzled], 16KB each

  bf16x8 qa[2][2];
#pragma unroll
  for (int f = 0; f < 2; f++) {
    const ushort_t* qp = &qr[hb + (size_t)(q0 + f * 16 + l16) * 64 + grp * 8];
    qa[f][0] = *reinterpret_cast<const bf16x8*>(qp);
    qa[f][1] = *reinterpret_cast<const bf16x8*>(qp + 32);
  }

  floatx4 o[2][4] = {};
  floatx4 ol[2] = {};     // ones-row accumulator: every reg = Sigma p for this lane's q

  union { ushort_t u[8]; bf16x8 v; } onef;
#pragma unroll
  for (int e = 0; e < 8; e++) onef.u[e] = 0x3F80;   // bf16 1.0

  auto stage = [&](int buf, int k0) {
    const ushort_t* kg = &kr[hb + (size_t)k0 * 64];
#pragma unroll
    for (int i = 0; i < 4; i++) {
      const int j = w * 4 + i;
      gl2lds16(kg + j * 512 + lane * 8, &sK[buf][j * 512]);
    }
#pragma unroll
    for (int i = 0; i < 4; i++) {
      const int d = w * 16 + i * 4;
      gl2lds16(&vt[((size_t)bh * 64 + d + (lane >> 4)) * 2048 + k0 + (lane & 15) * 8],
               &sV[buf][d * 128]);
    }
  };

  stage(0, 0);
  const int g0 = (grp ^ sw) * 8;
  for (int it = 0; it < 16; it++) {
    const int cur = it & 1;
    __syncthreads();
    if (it + 1 < 16) stage(1 - cur, (it + 1) * 128);
#pragma unroll
    for (int hh = 0; hh < 2; hh++) {
      const ushort_t* kb = &sK[cur][hh * 64 * 64];
      const ushort_t* vb = &sV[cur][hh * 64];
      floatx4 s[2][4];
#pragma unroll
      for (int nt = 0; nt < 4; nt++) {
        const ushort_t* kp = kb + (nt * 16 + l16) * 64;
        bf16x8 kf0 = *reinterpret_cast<const bf16x8*>(kp + g0);
        bf16x8 kf1 = *reinterpret_cast<const bf16x8*>(kp + (g0 ^ 32));
#pragma unroll
        for (int f = 0; f < 2; f++) {
          floatx4 acc = {};
          acc = __builtin_amdgcn_mfma_f32_16x16x32_bf16(kf0, qa[f][0], acc, 0, 0, 0);
          acc = __builtin_amdgcn_mfma_f32_16x16x32_bf16(kf1, qa[f][1], acc, 0, 0, 0);
          s[f][nt] = acc;
        }
      }
      union { unsigned int u32[4]; bf16x8 v; } pf[2][2];
#pragma unroll
      for (int f = 0; f < 2; f++) {
        float p[4][4];
#pragma unroll
        for (int nt = 0; nt < 4; nt++)
#pragma unroll
          for (int r = 0; r < 4; r++)
            p[nt][r] = __builtin_amdgcn_exp2f(s[f][nt][r]);
#pragma unroll
        for (int c = 0; c < 2; c++) {
          pf[f][c].u32[0] = pkbf(p[2 * c][0], p[2 * c][1]);
          pf[f][c].u32[1] = pkbf(p[2 * c][2], p[2 * c][3]);
          pf[f][c].u32[2] = pkbf(p[2 * c + 1][0], p[2 * c + 1][1]);
          pf[f][c].u32[3] = pkbf(p[2 * c + 1][2], p[2 * c + 1][3]);
        }
      }
#pragma unroll
      for (int c = 0; c < 2; c++) {
#pragma unroll
        for (int f = 0; f < 2; f++)
          ol[f] = __builtin_amdgcn_mfma_f32_16x16x32_bf16(onef.v, pf[f][c].v, ol[f], 0, 0, 0);
#pragma unroll
        for (int dt = 0; dt < 4; dt++) {
          const bf16x8 vv = *reinterpret_cast<const bf16x8*>(
              vb + (dt * 16 + l16) * 128 + (((c * 4 + grp) ^ sw) << 3));
#pragma unroll
          for (int f = 0; f < 2; f++)
            o[f][dt] = __builtin_amdgcn_mfma_f32_16x16x32_bf16(vv, pf[f][c].v, o[f][dt], 0, 0, 0);
        }
      }
    }
  }
  const int b = bh >> 4, h = bh & 15;
#pragma unroll
  for (int f = 0; f < 2; f++) {
    const float rl = 1.0f / ol[f][0];
    const size_t orow = (size_t)(b * 2048 + q0 + f * 16 + l16) * 1024 + h * 64;
#pragma unroll
    for (int dt = 0; dt < 4; dt++) {
      uint2 ov = make_uint2(pkbf(o[f][dt][0] * rl, o[f][dt][1] * rl),
                            pkbf(o[f][dt][2] * rl, o[f][dt][3] * rl));
      *reinterpret_cast<uint2*>(&aout[orow + dt * 16 + grp * 4]) = ov;
    }
  }
}

// ---------------- proj GEMM (BK=64, swizzled): out = a_out @ proj_w^T + b (fp32) ----------------
// grid (mtile=x 32, ntile=y 16): per-XCD working set A 1MB + B 2MB fits L2.
__global__ __launch_bounds__(256)
void gemm_proj(const ushort_t* __restrict__ A, const ushort_t* __restrict__ B,
               float* __restrict__ Cout, const float* __restrict__ bias) {
  const int K = 1024, N = 1024;
  __shared__ __align__(16) ushort_t sA[8192];   // 128x64
  __shared__ __align__(16) ushort_t sB[4096];   // 64x64
  __shared__ float sT[4][2048];                 // per-wave 64x32 fp32 (8KB each)
  const int m0 = blockIdx.x * 128, n0 = blockIdx.y * 64;   // XCD-pinned m
  const int tid = threadIdx.x;
  const int lane = tid & 63, w = tid >> 6;
  const int wm = (w >> 1) * 64, wn = (w & 1) * 32;
  const int grp = lane >> 4, l16 = lane & 15;
  const int r8 = lane >> 3;
  const int c8 = ((lane & 7) ^ r8) * 8;
  floatx4 acc[4][2] = {};
  for (int k0 = 0; k0 < K; k0 += 64) {
    __syncthreads();
#pragma unroll
    for (int i = 0; i < 4; i++) {
      const int j = w * 4 + i;
      gl2lds16(&A[(size_t)(m0 + j * 8 + r8) * K + k0 + c8], &sA[j * 512]);
    }
#pragma unroll
    for (int i = 0; i < 2; i++) {
      const int j = w * 2 + i;
      gl2lds16(&B[(size_t)(n0 + j * 8 + r8) * K + k0 + c8], &sB[j * 512]);
    }
    __syncthreads();
#pragma unroll
    for (int kk = 0; kk < 2; kk++) {
      bf16x8 af[4], bfr[2];
#pragma unroll
      for (int i = 0; i < 4; i++) {
        const int ra = wm + i * 16 + l16;
        af[i] = *reinterpret_cast<const bf16x8*>(
            &sA[ra * 64 + (((kk * 4 + grp) ^ (ra & 7)) << 3)]);
      }
#pragma unroll
      for (int j = 0; j < 2; j++) {
        const int rb = wn + j * 16 + l16;
        bfr[j] = *reinterpret_cast<const bf16x8*>(
            &sB[rb * 64 + (((kk * 4 + grp) ^ (rb & 7)) << 3)]);
      }
#pragma unroll
      for (int i = 0; i < 4; i++)
#pragma unroll
        for (int j = 0; j < 2; j++)
          acc[i][j] = __builtin_amdgcn_mfma_f32_16x16x32_bf16(af[i], bfr[j], acc[i][j], 0, 0, 0);
    }
  }
  // phase A: bias + store to per-wave LDS tile, 4B-chunk swizzle by row&7
  float bv[2];
#pragma unroll
  for (int j = 0; j < 2; j++) bv[j] = bias[n0 + wn + j * 16 + l16];
#pragma unroll
  for (int i = 0; i < 4; i++)
#pragma unroll
    for (int j = 0; j < 2; j++) {
      const int col = j * 16 + l16, c4 = col >> 2;
#pragma unroll
      for (int rr = 0; rr < 4; rr++) {
        const int row = i * 16 + grp * 4 + rr;
        sT[w][row * 32 + ((c4 ^ (row & 7)) << 2) + (col & 3)] = acc[i][j][rr] + bv[j];
      }
    }
  __builtin_amdgcn_s_waitcnt(0);   // per-wave tile: LDS writes before reads
  const int lr = lane >> 3, ch = lane & 7;
#pragma unroll
  for (int rg = 0; rg < 8; rg++) {
    const int row = rg * 8 + lr;
    float4 vvv = *(const float4*)&sT[w][row * 32 + ((ch ^ (row & 7)) << 2)];
    *reinterpret_cast<float4*>(&Cout[(size_t)(m0 + wm + row) * N + n0 + wn + ch * 4]) = vvv;
  }
}

extern "C" void kernel_launch(void* const* d_in, const int* in_sizes, int n_in,
                              void* d_out, int out_size, void* d_ws, size_t ws_size,
                              hipStream_t stream) {
  const float* x      = (const float*)d_in[0];   // [2,2048,1024]
  const float* pos    = (const float*)d_in[1];   // [2048,32]
  const float* qkv_w  = (const float*)d_in[2];   // [3072,1024]
  const float* q_nw   = (const float*)d_in[3];   // [64]
  const float* k_nw   = (const float*)d_in[4];   // [64]
  const float* proj_w = (const float*)d_in[5];   // [1024,1024]
  const float* proj_b = (const float*)d_in[6];   // [1024]
  float* out = (float*)d_out;                    // [2,2048,1024] fp32

  ushort_t* x_b     = (ushort_t*)d_ws;                         // 4096*1024
  ushort_t* qkvw_b  = x_b     + (size_t)4096 * 1024;           // 3072*1024
  ushort_t* projw_b = qkvw_b  + (size_t)3072 * 1024;           // 1024*1024
  ushort_t* q_r     = projw_b + (size_t)1024 * 1024;           // 32*2048*64
  ushort_t* k_r     = q_r     + (size_t)32 * 2048 * 64;
  ushort_t* v_t     = k_r     + (size_t)32 * 2048 * 64;
  ushort_t* a_out   = v_t     + (size_t)32 * 2048 * 64;        // 4096*1024
  float*    cs_tab  = (float*)(a_out + (size_t)4096 * 1024);   // 65536*2 fp32 (512KB)

  cast_all<<<8388608 / 4 / 256, 256, 0, stream>>>(x, qkv_w, proj_w, x_b, pos, cs_tab);

  gemm_qkv_fused<<<dim3(4096 / 128, 3072 / 128), 256, 0, stream>>>(
      x_b, qkvw_b, cs_tab, q_nw, k_nw, q_r, k_r, v_t);

  flash_attn<<<dim3(32, 2048 / 128), 256, 0, stream>>>(q_r, k_r, v_t, a_out);

  gemm_proj<<<dim3(4096 / 128, 1024 / 64), 256, 0, stream>>>(a_out, projw_b, out, proj_b);
}

// Round 11
// 188.924 us; speedup vs baseline: 2.7507x; 1.0372x over previous
//
#include <hip/hip_runtime.h>
#include <hip/hip_bf16.h>

typedef unsigned short ushort_t;
using floatx4 = __attribute__((__ext_vector_type__(4))) float;
using bf16x8  = __attribute__((__ext_vector_type__(8))) __bf16;
using ushort4v = __attribute__((__ext_vector_type__(4))) ushort_t;

// packed f32x2 -> bf16x2 (v_cvt_pk_bf16_f32); memcpy because __hip_bfloat162
// is not trivially copyable
__device__ __forceinline__ unsigned int pkbf(float a, float b) {
  __hip_bfloat162 h = __float22bfloat162_rn(make_float2(a, b));
  unsigned int u;
  __builtin_memcpy(&u, &h, 4);
  return u;
}

// async global->LDS, 16B per lane; lds dest is wave-uniform base (HW adds lane*16)
__device__ __forceinline__ void gl2lds16(const ushort_t* g, ushort_t* l) {
  __builtin_amdgcn_global_load_lds(
      (const __attribute__((address_space(1))) unsigned int*)g,
      (__attribute__((address_space(3))) unsigned int*)l, 16, 0, 0);
}

// ---------------- merged cast fp32 -> bf16 of x, qkv_w, proj_w + cos/sin table ----------------
__global__ void cast_all(const float* __restrict__ x, const float* __restrict__ qw,
                         const float* __restrict__ pw, ushort_t* __restrict__ ob,
                         const float* __restrict__ pos, float* __restrict__ cs) {
  const int T1 = 4096 * 1024, T2 = T1 + 3072 * 1024, T3 = T2 + 1024 * 1024;
  const int tid = blockIdx.x * blockDim.x + threadIdx.x;
  if (tid < 65536) {              // 2048 tokens x 32 angles
    const float a = pos[tid];
    cs[2 * tid]     = __cosf(a);
    cs[2 * tid + 1] = __sinf(a);
  }
  const int i = tid * 4;
  if (i < T3) {
    const float* src = (i < T1) ? (x + i) : (i < T2) ? (qw + (i - T1)) : (pw + (i - T2));
    float4 v = *reinterpret_cast<const float4*>(src);
    uint2 o = make_uint2(pkbf(v.x, v.y), pkbf(v.z, v.w));
    *reinterpret_cast<uint2*>(&ob[i]) = o;
  }
}

// ---------------- QKV GEMM (BK=64, swizzled LDS) + fused RMSNorm/rotary/relayout ----------------
// grid (mtile=x, ntile=y): id%8 = mtile%8 pins 4 A-tiles (1MB) per XCD, reused 24x in L2.
__global__ __launch_bounds__(256)
void gemm_qkv_fused(const ushort_t* __restrict__ A, const ushort_t* __restrict__ B,
                    const float* __restrict__ cs,
                    const float* __restrict__ qnw, const float* __restrict__ knw,
                    ushort_t* __restrict__ qr, ushort_t* __restrict__ kr,
                    ushort_t* __restrict__ vt) {
  const int K = 1024;
  __shared__ __align__(16) ushort_t smem[16384];   // 32KB: sA | sB, aliased by sE
  ushort_t* sA = smem;
  ushort_t* sB = smem + 8192;
  const int m0 = blockIdx.x * 128, n0 = blockIdx.y * 128;   // XCD-pinned m
  const int tid = threadIdx.x;
  const int lane = tid & 63, w = tid >> 6;
  const int wm = (w >> 1) * 64;
  const int grp = lane >> 4, l16 = lane & 15;
  const int r8 = lane >> 3;                         // row-in-chunk for staging
  const int c8 = ((lane & 7) ^ r8) * 8;             // swizzled source col (elems)
  floatx4 acc[4][4] = {};
  for (int k0 = 0; k0 < K; k0 += 64) {
    __syncthreads();
#pragma unroll
    for (int i = 0; i < 4; i++) {
      const int j = w * 4 + i;                      // chunk 0..15 (8 rows x 128B)
      gl2lds16(&A[(size_t)(m0 + j * 8 + r8) * K + k0 + c8], &sA[j * 512]);
      gl2lds16(&B[(size_t)(n0 + j * 8 + r8) * K + k0 + c8], &sB[j * 512]);
    }
    __syncthreads();
#pragma unroll
    for (int kk = 0; kk < 2; kk++) {
      bf16x8 af[4], bfr[4];
#pragma unroll
      for (int i = 0; i < 4; i++) {
        const int ra = wm + i * 16 + l16;
        af[i] = *reinterpret_cast<const bf16x8*>(
            &sA[ra * 64 + (((kk * 4 + grp) ^ (ra & 7)) << 3)]);
      }
#pragma unroll
      for (int i = 0; i < 4; i++) {
        const int rb = (w & 1) * 64 + i * 16 + l16;
        bfr[i] = *reinterpret_cast<const bf16x8*>(
            &sB[rb * 64 + (((kk * 4 + grp) ^ (rb & 7)) << 3)]);
      }
#pragma unroll
      for (int i = 0; i < 4; i++)
#pragma unroll
        for (int j = 0; j < 4; j++)
          acc[i][j] = __builtin_amdgcn_mfma_f32_16x16x32_bf16(af[i], bfr[j], acc[i][j], 0, 0, 0);
    }
  }
  __syncthreads();                 // all K-loop LDS reads done before epilogue overwrites
  // ---- fused epilogue (per-wave 8KB tile aliased over sA/sB) ----
  ushort_t* sE = smem + w * 4096;
  const int region = n0 >> 10;                 // 0=q,1=k,2=v
  const int h = ((n0 & 1023) >> 6) + (w & 1);  // head this wave owns
  const int tbase = m0 + wm;
  const int bb = tbase >> 11;
  const int nwin = tbase & 2047;
  const int q = lane & 7;
  const int lr = lane >> 3;

  if (region < 2) {
    float* sEf = (float*)sE;                   // 32 tokens x 64 dims fp32 (8KB)
    const float* nwp = (region == 0) ? qnw : knw;
    const float qmul = (region == 0) ? 0.125f * 1.44269504088896340736f : 1.0f;
    float wgt[8];
    *(float4*)&wgt[0] = *(const float4*)&nwp[q * 8];
    *(float4*)&wgt[4] = *(const float4*)&nwp[q * 8 + 4];
#pragma unroll
    for (int hf = 0; hf < 2; hf++) {
      __builtin_amdgcn_s_waitcnt(0);           // prior per-wave LDS reads complete
      // phase A: dump fp32 [t2][d] with 16B-chunk XOR swizzle by t2&15
#pragma unroll
      for (int i2 = 0; i2 < 2; i2++)
#pragma unroll
        for (int rr = 0; rr < 4; rr++) {
          const int t2 = i2 * 16 + grp * 4 + rr;
#pragma unroll
          for (int j = 0; j < 4; j++) {
            const int cd = (j * 4 + (l16 >> 2)) ^ (t2 & 15);
            sEf[t2 * 64 + cd * 4 + (l16 & 3)] = acc[hf * 2 + i2][j][rr];
          }
        }
      __builtin_amdgcn_s_waitcnt(0);
      // phase B: 8 lanes per token; lane handles dims [8q, 8q+8)
#pragma unroll
      for (int tg = 0; tg < 4; tg++) {
        const int t2 = tg * 8 + lr;
        const int n = (tbase + hf * 32 + t2) & 2047;
        float v0[8];
        const int ck1 = (2 * q) ^ (t2 & 15), ck2 = (2 * q + 1) ^ (t2 & 15);
        *(float4*)&v0[0] = *(const float4*)&sEf[t2 * 64 + ck1 * 4];
        *(float4*)&v0[4] = *(const float4*)&sEf[t2 * 64 + ck2 * 4];
        float ss = 0.f;
#pragma unroll
        for (int e = 0; e < 8; e++) ss += v0[e] * v0[e];
        ss += __shfl_xor(ss, 1); ss += __shfl_xor(ss, 2); ss += __shfl_xor(ss, 4);
        const float rn = rsqrtf(ss * (1.0f / 64.0f) + 1e-6f);
        float4 c01 = *(const float4*)&cs[(n * 32 + q * 4) * 2];
        float4 c23 = *(const float4*)&cs[(n * 32 + q * 4) * 2 + 4];
        float ccv[4] = {c01.x, c01.z, c23.x, c23.z};
        float snv[4] = {c01.y, c01.w, c23.y, c23.w};
        union { unsigned int u32[4]; uint4 v4; } ov;
#pragma unroll
        for (int p = 0; p < 4; p++) {
          const float cc = ccv[p], sn = snv[p];
          const float xr = v0[2 * p] * rn * wgt[2 * p];
          const float xi = v0[2 * p + 1] * rn * wgt[2 * p + 1];
          ov.u32[p] = pkbf((xr * cc - xi * sn) * qmul, (xr * sn + xi * cc) * qmul);
        }
        const size_t rowb = ((size_t)(bb * 16 + h) * 2048 + n) * 64;
        if (region == 0)
          *reinterpret_cast<uint4*>(&qr[rowb + q * 8]) = ov.v4;
        else
          *reinterpret_cast<uint4*>(&kr[rowb + (q ^ (n & 7)) * 8]) = ov.v4;
      }
    }
  } else {
    // v region: LDS [d][t] bf16, rr-quads packed as b64; 8B-chunk swizzle by d&15
#pragma unroll
    for (int i = 0; i < 4; i++)
#pragma unroll
      for (int j = 0; j < 4; j++) {
        const int d = j * 16 + l16;
        const int ct = (i * 4 + grp) ^ (d & 15);
        uint2 pk = make_uint2(pkbf(acc[i][j][0], acc[i][j][1]),
                              pkbf(acc[i][j][2], acc[i][j][3]));
        *reinterpret_cast<uint2*>(&sE[d * 64 + ct * 4]) = pk;
      }
    __builtin_amdgcn_s_waitcnt(0);
#pragma unroll
    for (int dd = 0; dd < 8; dd++) {
      const int d = dd * 8 + lr;
      const int cta = 8 * (q >> 2) + (q & 3);        // token-run chunks (t1, t1+16)
      union { ushort4v hh[2]; uint4 v4; } ob;
      ob.hh[0] = *reinterpret_cast<const ushort4v*>(&sE[d * 64 + ((cta ^ (d & 15)) * 4)]);
      ob.hh[1] = *reinterpret_cast<const ushort4v*>(&sE[d * 64 + (((cta + 4) ^ (d & 15)) * 4)]);
      *reinterpret_cast<uint4*>(
          &vt[((size_t)(bb * 16 + h) * 64 + d) * 2048 + nwin + (q ^ (d & 7)) * 8]) = ob.v4;
    }
  }
}

// ---------------- Flash attention v6: 8-wave blocks (16 waves/CU), 128-key tiles ----------------
// grid (bh=x 32, qtile=y 16), block 512 = 8 waves x 16 q-rows. 2 blocks/CU x 8 waves
// = 16 waves/CU so exp2 (trans pipe, ~half the wall at R10) overlaps MFMA across waves.
// No running max: ||q||=||k||=8 after RMSNorm => |score*log2e*scale| <= 11.6, exp2-safe.
__global__ __launch_bounds__(512)
void flash_attn(const ushort_t* __restrict__ qr, const ushort_t* __restrict__ kr,
                const ushort_t* __restrict__ vt, ushort_t* __restrict__ aout) {
  const int bh = blockIdx.x;
  const int w = threadIdx.x >> 6, lane = threadIdx.x & 63;
  const int grp = lane >> 4, l16 = lane & 15;
  const int sw = l16 & 7;
  const int q0 = blockIdx.y * 128 + w * 16;   // 16 q-rows per wave
  const size_t hb = (size_t)bh * 2048 * 64;

  __shared__ ushort_t sK[2][128 * 64];   // [key][d-swizzled], 16KB each
  __shared__ ushort_t sV[2][64 * 128];   // [d][128-key window permuted+swizzled], 16KB each

  // Q as MFMA B-operand: lane holds Q[q0+l16][grp*8 + j]
  const ushort_t* qp = &qr[hb + (size_t)(q0 + l16) * 64 + grp * 8];
  const bf16x8 qa0 = *reinterpret_cast<const bf16x8*>(qp);
  const bf16x8 qa1 = *reinterpret_cast<const bf16x8*>(qp + 32);

  floatx4 o[4] = {};
  floatx4 ol = {};        // ones-row accumulator: every reg = Sigma p for this lane's q

  union { ushort_t u[8]; bf16x8 v; } onef;
#pragma unroll
  for (int e = 0; e < 8; e++) onef.u[e] = 0x3F80;   // bf16 1.0

  auto stage = [&](int buf, int k0) {
    const ushort_t* kg = &kr[hb + (size_t)k0 * 64];
#pragma unroll
    for (int i = 0; i < 2; i++) {
      const int j = w * 2 + i;               // K chunk: rows j*8..j*8+7 (1KB)
      gl2lds16(kg + j * 512 + lane * 8, &sK[buf][j * 512]);
    }
#pragma unroll
    for (int i = 0; i < 2; i++) {
      const int d = (w * 2 + i) * 4;         // V chunk: d-rows d..d+3 (1KB)
      gl2lds16(&vt[((size_t)bh * 64 + d + (lane >> 4)) * 2048 + k0 + (lane & 15) * 8],
               &sV[buf][d * 128]);
    }
  };

  stage(0, 0);
  const int g0 = (grp ^ sw) * 8;
  for (int it = 0; it < 16; it++) {
    const int cur = it & 1;
    __syncthreads();
    if (it + 1 < 16) stage(1 - cur, (it + 1) * 128);
#pragma unroll
    for (int hh = 0; hh < 2; hh++) {
      const ushort_t* kb = &sK[cur][hh * 64 * 64];
      const ushort_t* vb = &sV[cur][hh * 64];
      floatx4 s[4];
#pragma unroll
      for (int nt = 0; nt < 4; nt++) {
        const ushort_t* kp = kb + (nt * 16 + l16) * 64;
        bf16x8 kf0 = *reinterpret_cast<const bf16x8*>(kp + g0);
        bf16x8 kf1 = *reinterpret_cast<const bf16x8*>(kp + (g0 ^ 32));
        floatx4 acc = {};
        acc = __builtin_amdgcn_mfma_f32_16x16x32_bf16(kf0, qa0, acc, 0, 0, 0);
        acc = __builtin_amdgcn_mfma_f32_16x16x32_bf16(kf1, qa1, acc, 0, 0, 0);
        s[nt] = acc;
      }
      float p[4][4];
#pragma unroll
      for (int nt = 0; nt < 4; nt++)
#pragma unroll
        for (int r = 0; r < 4; r++)
          p[nt][r] = __builtin_amdgcn_exp2f(s[nt][r]);
      union { unsigned int u32[4]; bf16x8 v; } pf[2];
#pragma unroll
      for (int c = 0; c < 2; c++) {
        pf[c].u32[0] = pkbf(p[2 * c][0], p[2 * c][1]);
        pf[c].u32[1] = pkbf(p[2 * c][2], p[2 * c][3]);
        pf[c].u32[2] = pkbf(p[2 * c + 1][0], p[2 * c + 1][1]);
        pf[c].u32[3] = pkbf(p[2 * c + 1][2], p[2 * c + 1][3]);
      }
#pragma unroll
      for (int c = 0; c < 2; c++) {
        ol = __builtin_amdgcn_mfma_f32_16x16x32_bf16(onef.v, pf[c].v, ol, 0, 0, 0);
#pragma unroll
        for (int dt = 0; dt < 4; dt++) {
          const bf16x8 vv = *reinterpret_cast<const bf16x8*>(
              vb + (dt * 16 + l16) * 128 + (((c * 4 + grp) ^ sw) << 3));
          o[dt] = __builtin_amdgcn_mfma_f32_16x16x32_bf16(vv, pf[c].v, o[dt], 0, 0, 0);
        }
      }
    }
  }
  const int b = bh >> 4, h = bh & 15;
  const float rl = 1.0f / ol[0];
  const size_t orow = (size_t)(b * 2048 + q0 + l16) * 1024 + h * 64;
#pragma unroll
  for (int dt = 0; dt < 4; dt++) {
    uint2 ov = make_uint2(pkbf(o[dt][0] * rl, o[dt][1] * rl),
                          pkbf(o[dt][2] * rl, o[dt][3] * rl));
    *reinterpret_cast<uint2*>(&aout[orow + dt * 16 + grp * 4]) = ov;
  }
}

// ---------------- proj GEMM (BK=64, swizzled): out = a_out @ proj_w^T + b (fp32) ----------------
// grid (mtile=x 32, ntile=y 16): per-XCD working set A 1MB + B 2MB fits L2.
__global__ __launch_bounds__(256)
void gemm_proj(const ushort_t* __restrict__ A, const ushort_t* __restrict__ B,
               float* __restrict__ Cout, const float* __restrict__ bias) {
  const int K = 1024, N = 1024;
  __shared__ __align__(16) ushort_t sA[8192];   // 128x64
  __shared__ __align__(16) ushort_t sB[4096];   // 64x64
  __shared__ float sT[4][2048];                 // per-wave 64x32 fp32 (8KB each)
  const int m0 = blockIdx.x * 128, n0 = blockIdx.y * 64;   // XCD-pinned m
  const int tid = threadIdx.x;
  const int lane = tid & 63, w = tid >> 6;
  const int wm = (w >> 1) * 64, wn = (w & 1) * 32;
  const int grp = lane >> 4, l16 = lane & 15;
  const int r8 = lane >> 3;
  const int c8 = ((lane & 7) ^ r8) * 8;
  floatx4 acc[4][2] = {};
  for (int k0 = 0; k0 < K; k0 += 64) {
    __syncthreads();
#pragma unroll
    for (int i = 0; i < 4; i++) {
      const int j = w * 4 + i;
      gl2lds16(&A[(size_t)(m0 + j * 8 + r8) * K + k0 + c8], &sA[j * 512]);
    }
#pragma unroll
    for (int i = 0; i < 2; i++) {
      const int j = w * 2 + i;
      gl2lds16(&B[(size_t)(n0 + j * 8 + r8) * K + k0 + c8], &sB[j * 512]);
    }
    __syncthreads();
#pragma unroll
    for (int kk = 0; kk < 2; kk++) {
      bf16x8 af[4], bfr[2];
#pragma unroll
      for (int i = 0; i < 4; i++) {
        const int ra = wm + i * 16 + l16;
        af[i] = *reinterpret_cast<const bf16x8*>(
            &sA[ra * 64 + (((kk * 4 + grp) ^ (ra & 7)) << 3)]);
      }
#pragma unroll
      for (int j = 0; j < 2; j++) {
        const int rb = wn + j * 16 + l16;
        bfr[j] = *reinterpret_cast<const bf16x8*>(
            &sB[rb * 64 + (((kk * 4 + grp) ^ (rb & 7)) << 3)]);
      }
#pragma unroll
      for (int i = 0; i < 4; i++)
#pragma unroll
        for (int j = 0; j < 2; j++)
          acc[i][j] = __builtin_amdgcn_mfma_f32_16x16x32_bf16(af[i], bfr[j], acc[i][j], 0, 0, 0);
    }
  }
  // phase A: bias + store to per-wave LDS tile, 4B-chunk swizzle by row&7
  float bv[2];
#pragma unroll
  for (int j = 0; j < 2; j++) bv[j] = bias[n0 + wn + j * 16 + l16];
#pragma unroll
  for (int i = 0; i < 4; i++)
#pragma unroll
    for (int j = 0; j < 2; j++) {
      const int col = j * 16 + l16, c4 = col >> 2;
#pragma unroll
      for (int rr = 0; rr < 4; rr++) {
        const int row = i * 16 + grp * 4 + rr;
        sT[w][row * 32 + ((c4 ^ (row & 7)) << 2) + (col & 3)] = acc[i][j][rr] + bv[j];
      }
    }
  __builtin_amdgcn_s_waitcnt(0);   // per-wave tile: LDS writes before reads
  const int lr = lane >> 3, ch = lane & 7;
#pragma unroll
  for (int rg = 0; rg < 8; rg++) {
    const int row = rg * 8 + lr;
    float4 vvv = *(const float4*)&sT[w][row * 32 + ((ch ^ (row & 7)) << 2)];
    *reinterpret_cast<float4*>(&Cout[(size_t)(m0 + wm + row) * N + n0 + wn + ch * 4]) = vvv;
  }
}

extern "C" void kernel_launch(void* const* d_in, const int* in_sizes, int n_in,
                              void* d_out, int out_size, void* d_ws, size_t ws_size,
                              hipStream_t stream) {
  const float* x      = (const float*)d_in[0];   // [2,2048,1024]
  const float* pos    = (const float*)d_in[1];   // [2048,32]
  const float* qkv_w  = (const float*)d_in[2];   // [3072,1024]
  const float* q_nw   = (const float*)d_in[3];   // [64]
  const float* k_nw   = (const float*)d_in[4];   // [64]
  const float* proj_w = (const float*)d_in[5];   // [1024,1024]
  const float* proj_b = (const float*)d_in[6];   // [1024]
  float* out = (float*)d_out;                    // [2,2048,1024] fp32

  ushort_t* x_b     = (ushort_t*)d_ws;                         // 4096*1024
  ushort_t* qkvw_b  = x_b     + (size_t)4096 * 1024;           // 3072*1024
  ushort_t* projw_b = qkvw_b  + (size_t)3072 * 1024;           // 1024*1024
  ushort_t* q_r     = projw_b + (size_t)1024 * 1024;           // 32*2048*64
  ushort_t* k_r     = q_r     + (size_t)32 * 2048 * 64;
  ushort_t* v_t     = k_r     + (size_t)32 * 2048 * 64;
  ushort_t* a_out   = v_t     + (size_t)32 * 2048 * 64;        // 4096*1024
  float*    cs_tab  = (float*)(a_out + (size_t)4096 * 1024);   // 65536*2 fp32 (512KB)

  cast_all<<<8388608 / 4 / 256, 256, 0, stream>>>(x, qkv_w, proj_w, x_b, pos, cs_tab);

  gemm_qkv_fused<<<dim3(4096 / 128, 3072 / 128), 256, 0, stream>>>(
      x_b, qkvw_b, cs_tab, q_nw, k_nw, q_r, k_r, v_t);

  flash_attn<<<dim3(32, 2048 / 128), 512, 0, stream>>>(q_r, k_r, v_t, a_out);

  gemm_proj<<<dim3(4096 / 128, 1024 / 64), 256, 0, stream>>>(a_out, projw_b, out, proj_b);
}

// Round 12
// 180.114 us; speedup vs baseline: 2.8853x; 1.0489x over previous
//
#include <hip/hip_runtime.h>
#include <hip/hip_bf16.h>

typedef unsigned short ushort_t;
using floatx4 = __attribute__((__ext_vector_type__(4))) float;
using bf16x8  = __attribute__((__ext_vector_type__(8))) __bf16;
using ushort4v = __attribute__((__ext_vector_type__(4))) ushort_t;

// packed f32x2 -> bf16x2 (v_cvt_pk_bf16_f32); memcpy because __hip_bfloat162
// is not trivially copyable
__device__ __forceinline__ unsigned int pkbf(float a, float b) {
  __hip_bfloat162 h = __float22bfloat162_rn(make_float2(a, b));
  unsigned int u;
  __builtin_memcpy(&u, &h, 4);
  return u;
}

// async global->LDS, 16B per lane; lds dest is wave-uniform base (HW adds lane*16)
__device__ __forceinline__ void gl2lds16(const ushort_t* g, ushort_t* l) {
  __builtin_amdgcn_global_load_lds(
      (const __attribute__((address_space(1))) unsigned int*)g,
      (__attribute__((address_space(3))) unsigned int*)l, 16, 0, 0);
}

// ---------------- merged cast fp32 -> bf16 of x, qkv_w, proj_w + cos/sin table ----------------
__global__ void cast_all(const float* __restrict__ x, const float* __restrict__ qw,
                         const float* __restrict__ pw, ushort_t* __restrict__ ob,
                         const float* __restrict__ pos, float* __restrict__ cs) {
  const int T1 = 4096 * 1024, T2 = T1 + 3072 * 1024, T3 = T2 + 1024 * 1024;
  const int tid = blockIdx.x * blockDim.x + threadIdx.x;
  if (tid < 65536) {              // 2048 tokens x 32 angles
    const float a = pos[tid];
    cs[2 * tid]     = __cosf(a);
    cs[2 * tid + 1] = __sinf(a);
  }
  const int i = tid * 4;
  if (i < T3) {
    const float* src = (i < T1) ? (x + i) : (i < T2) ? (qw + (i - T1)) : (pw + (i - T2));
    float4 v = *reinterpret_cast<const float4*>(src);
    uint2 o = make_uint2(pkbf(v.x, v.y), pkbf(v.z, v.w));
    *reinterpret_cast<uint2*>(&ob[i]) = o;
  }
}

// ---------------- QKV GEMM v3: 8-wave blocks, 32x64 per wave + fused epilogue ----------------
// 512 threads, 8 waves: wave w owns m-rows (w>>1)*32.., n-cols (w&1)*64.. (one full head).
// grid (mtile=x 32, ntile=y 24): id%8 pins A-tiles per XCD. LDS 32KB swizzled; the
// per-wave 4KB epilogue tiles alias sA|sB after the K-loop.
__global__ __launch_bounds__(512)
void gemm_qkv_fused(const ushort_t* __restrict__ A, const ushort_t* __restrict__ B,
                    const float* __restrict__ cs,
                    const float* __restrict__ qnw, const float* __restrict__ knw,
                    ushort_t* __restrict__ qr, ushort_t* __restrict__ kr,
                    ushort_t* __restrict__ vt) {
  const int K = 1024;
  __shared__ __align__(16) ushort_t smem[16384];   // 32KB: sA(16K) | sB(16K), aliased by sE
  ushort_t* sA = smem;
  ushort_t* sB = smem + 8192;
  const int m0 = blockIdx.x * 128, n0 = blockIdx.y * 128;
  const int tid = threadIdx.x;
  const int lane = tid & 63, w = tid >> 6;          // w in [0,8)
  const int wm = (w >> 1) * 32;
  const int grp = lane >> 4, l16 = lane & 15;
  const int r8 = lane >> 3;
  const int c8 = ((lane & 7) ^ r8) * 8;
  floatx4 acc[2][4] = {};
  for (int k0 = 0; k0 < K; k0 += 64) {
    __syncthreads();
#pragma unroll
    for (int i = 0; i < 2; i++) {
      const int j = w * 2 + i;                      // chunk 0..15 (8 rows x 128B)
      gl2lds16(&A[(size_t)(m0 + j * 8 + r8) * K + k0 + c8], &sA[j * 512]);
      gl2lds16(&B[(size_t)(n0 + j * 8 + r8) * K + k0 + c8], &sB[j * 512]);
    }
    __syncthreads();
#pragma unroll
    for (int kk = 0; kk < 2; kk++) {
      bf16x8 af[2], bfr[4];
#pragma unroll
      for (int i = 0; i < 2; i++) {
        const int ra = wm + i * 16 + l16;
        af[i] = *reinterpret_cast<const bf16x8*>(
            &sA[ra * 64 + (((kk * 4 + grp) ^ (ra & 7)) << 3)]);
      }
#pragma unroll
      for (int j = 0; j < 4; j++) {
        const int rb = (w & 1) * 64 + j * 16 + l16;
        bfr[j] = *reinterpret_cast<const bf16x8*>(
            &sB[rb * 64 + (((kk * 4 + grp) ^ (rb & 7)) << 3)]);
      }
#pragma unroll
      for (int i = 0; i < 2; i++)
#pragma unroll
        for (int j = 0; j < 4; j++)
          acc[i][j] = __builtin_amdgcn_mfma_f32_16x16x32_bf16(af[i], bfr[j], acc[i][j], 0, 0, 0);
    }
  }
  __syncthreads();                 // all K-loop LDS reads done before epilogue overwrites
  // ---- fused epilogue: per-wave 4KB tile at smem + w*4KB ----
  ushort_t* sE = smem + w * 2048;
  const int region = n0 >> 10;                 // 0=q,1=k,2=v
  const int h = ((n0 & 1023) >> 6) + (w & 1);  // head this wave owns
  const int tbase = m0 + wm;                   // 32-aligned token base
  const int bb = tbase >> 11;
  const int q = lane & 7;
  const int lr = lane >> 3;

  if (region < 2) {
    float* sEf = (float*)sE;                   // 16 tokens x 64 dims fp32 (4KB)
    const float* nwp = (region == 0) ? qnw : knw;
    const float qmul = (region == 0) ? 0.125f * 1.44269504088896340736f : 1.0f;
    float wgt[8];
    *(float4*)&wgt[0] = *(const float4*)&nwp[q * 8];
    *(float4*)&wgt[4] = *(const float4*)&nwp[q * 8 + 4];
#pragma unroll
    for (int p = 0; p < 2; p++) {              // 2 passes x 16 tokens
      __builtin_amdgcn_s_waitcnt(0);
      // phase A: dump fp32 [t2][d], 16B-chunk XOR swizzle by t2
#pragma unroll
      for (int rr = 0; rr < 4; rr++) {
        const int t2 = grp * 4 + rr;
#pragma unroll
        for (int j = 0; j < 4; j++) {
          const int cd = (j * 4 + (l16 >> 2)) ^ t2;
          sEf[t2 * 64 + cd * 4 + (l16 & 3)] = acc[p][j][rr];
        }
      }
      __builtin_amdgcn_s_waitcnt(0);
      // phase B: 8 lanes per token; lane handles dims [8q, 8q+8)
#pragma unroll
      for (int tg = 0; tg < 2; tg++) {
        const int t2 = tg * 8 + lr;
        const int n = (tbase + p * 16 + t2) & 2047;
        float v0[8];
        const int ck1 = (2 * q) ^ t2, ck2 = (2 * q + 1) ^ t2;
        *(float4*)&v0[0] = *(const float4*)&sEf[t2 * 64 + ck1 * 4];
        *(float4*)&v0[4] = *(const float4*)&sEf[t2 * 64 + ck2 * 4];
        float ss = 0.f;
#pragma unroll
        for (int e = 0; e < 8; e++) ss += v0[e] * v0[e];
        ss += __shfl_xor(ss, 1); ss += __shfl_xor(ss, 2); ss += __shfl_xor(ss, 4);
        const float rn = rsqrtf(ss * (1.0f / 64.0f) + 1e-6f);
        float4 c01 = *(const float4*)&cs[(n * 32 + q * 4) * 2];
        float4 c23 = *(const float4*)&cs[(n * 32 + q * 4) * 2 + 4];
        float ccv[4] = {c01.x, c01.z, c23.x, c23.z};
        float snv[4] = {c01.y, c01.w, c23.y, c23.w};
        union { unsigned int u32[4]; uint4 v4; } ov;
#pragma unroll
        for (int pp = 0; pp < 4; pp++) {
          const float cc = ccv[pp], sn = snv[pp];
          const float xr = v0[2 * pp] * rn * wgt[2 * pp];
          const float xi = v0[2 * pp + 1] * rn * wgt[2 * pp + 1];
          ov.u32[pp] = pkbf((xr * cc - xi * sn) * qmul, (xr * sn + xi * cc) * qmul);
        }
        const size_t rowb = ((size_t)(bb * 16 + h) * 2048 + n) * 64;
        if (region == 0)
          *reinterpret_cast<uint4*>(&qr[rowb + q * 8]) = ov.v4;
        else
          *reinterpret_cast<uint4*>(&kr[rowb + (q ^ (n & 7)) * 8]) = ov.v4;
      }
    }
  } else {
    // v region: per-wave [d][32-token] bf16 tile (4KB), rr-quads as b64,
    // 8B-chunk swizzle by d&7. Wave covers half a 64-key window (contiguous
    // permuted half: token t2 -> lidx = grp*8 + i*4 + rr).
    const int nw_ = tbase & 2047;
    const int n64 = nw_ & ~63;
    const int hw = (nw_ >> 5) & 1;             // which half of the window
#pragma unroll
    for (int i = 0; i < 2; i++)
#pragma unroll
      for (int j = 0; j < 4; j++) {
        const int d = j * 16 + l16;
        const int ct = (grp * 2 + i) ^ (d & 7);
        uint2 pk = make_uint2(pkbf(acc[i][j][0], acc[i][j][1]),
                              pkbf(acc[i][j][2], acc[i][j][3]));
        *reinterpret_cast<uint2*>(&sE[d * 32 + ct * 4]) = pk;
      }
    __builtin_amdgcn_s_waitcnt(0);
    // phase B: lane -> (d = dd*16 + lane>>2, lc = lane&3): one 16B granule
    const int lc = lane & 3;
#pragma unroll
    for (int dd = 0; dd < 4; dd++) {
      const int d = dd * 16 + (lane >> 2);
      union { ushort4v hh[2]; uint4 v4; } ob;
      ob.hh[0] = *reinterpret_cast<const ushort4v*>(&sE[d * 32 + (((2 * lc) ^ (d & 7)) * 4)]);
      ob.hh[1] = *reinterpret_cast<const ushort4v*>(&sE[d * 32 + (((2 * lc + 1) ^ (d & 7)) * 4)]);
      *reinterpret_cast<uint4*>(
          &vt[((size_t)(bb * 16 + h) * 64 + d) * 2048 + n64 + (((hw * 4 + lc) ^ (d & 7)) * 8)]) = ob.v4;
    }
  }
}

// ---------------- Flash attention: 8-wave blocks (16 waves/CU), 128-key tiles ----------------
// grid (bh=x 32, qtile=y 16), block 512 = 8 waves x 16 q-rows. XCD-pinned bh.
// No running max: ||q||=||k||=8 after RMSNorm => |score*log2e*scale| <= 11.6, exp2-safe.
__global__ __launch_bounds__(512)
void flash_attn(const ushort_t* __restrict__ qr, const ushort_t* __restrict__ kr,
                const ushort_t* __restrict__ vt, ushort_t* __restrict__ aout) {
  const int bh = blockIdx.x;
  const int w = threadIdx.x >> 6, lane = threadIdx.x & 63;
  const int grp = lane >> 4, l16 = lane & 15;
  const int sw = l16 & 7;
  const int q0 = blockIdx.y * 128 + w * 16;   // 16 q-rows per wave
  const size_t hb = (size_t)bh * 2048 * 64;

  __shared__ ushort_t sK[2][128 * 64];   // [key][d-swizzled], 16KB each
  __shared__ ushort_t sV[2][64 * 128];   // [d][128-key window permuted+swizzled], 16KB each

  const ushort_t* qp = &qr[hb + (size_t)(q0 + l16) * 64 + grp * 8];
  const bf16x8 qa0 = *reinterpret_cast<const bf16x8*>(qp);
  const bf16x8 qa1 = *reinterpret_cast<const bf16x8*>(qp + 32);

  floatx4 o[4] = {};
  floatx4 ol = {};        // ones-row accumulator: every reg = Sigma p for this lane's q

  union { ushort_t u[8]; bf16x8 v; } onef;
#pragma unroll
  for (int e = 0; e < 8; e++) onef.u[e] = 0x3F80;   // bf16 1.0

  auto stage = [&](int buf, int k0) {
    const ushort_t* kg = &kr[hb + (size_t)k0 * 64];
#pragma unroll
    for (int i = 0; i < 2; i++) {
      const int j = w * 2 + i;               // K chunk: rows j*8..j*8+7 (1KB)
      gl2lds16(kg + j * 512 + lane * 8, &sK[buf][j * 512]);
    }
#pragma unroll
    for (int i = 0; i < 2; i++) {
      const int d = (w * 2 + i) * 4;         // V chunk: d-rows d..d+3 (1KB)
      gl2lds16(&vt[((size_t)bh * 64 + d + (lane >> 4)) * 2048 + k0 + (lane & 15) * 8],
               &sV[buf][d * 128]);
    }
  };

  stage(0, 0);
  const int g0 = (grp ^ sw) * 8;
  for (int it = 0; it < 16; it++) {
    const int cur = it & 1;
    __syncthreads();
    if (it + 1 < 16) stage(1 - cur, (it + 1) * 128);
#pragma unroll
    for (int hh = 0; hh < 2; hh++) {
      const ushort_t* kb = &sK[cur][hh * 64 * 64];
      const ushort_t* vb = &sV[cur][hh * 64];
      floatx4 s[4];
#pragma unroll
      for (int nt = 0; nt < 4; nt++) {
        const ushort_t* kp = kb + (nt * 16 + l16) * 64;
        bf16x8 kf0 = *reinterpret_cast<const bf16x8*>(kp + g0);
        bf16x8 kf1 = *reinterpret_cast<const bf16x8*>(kp + (g0 ^ 32));
        floatx4 acc = {};
        acc = __builtin_amdgcn_mfma_f32_16x16x32_bf16(kf0, qa0, acc, 0, 0, 0);
        acc = __builtin_amdgcn_mfma_f32_16x16x32_bf16(kf1, qa1, acc, 0, 0, 0);
        s[nt] = acc;
      }
      float p[4][4];
#pragma unroll
      for (int nt = 0; nt < 4; nt++)
#pragma unroll
        for (int r = 0; r < 4; r++)
          p[nt][r] = __builtin_amdgcn_exp2f(s[nt][r]);
      union { unsigned int u32[4]; bf16x8 v; } pf[2];
#pragma unroll
      for (int c = 0; c < 2; c++) {
        pf[c].u32[0] = pkbf(p[2 * c][0], p[2 * c][1]);
        pf[c].u32[1] = pkbf(p[2 * c][2], p[2 * c][3]);
        pf[c].u32[2] = pkbf(p[2 * c + 1][0], p[2 * c + 1][1]);
        pf[c].u32[3] = pkbf(p[2 * c + 1][2], p[2 * c + 1][3]);
      }
#pragma unroll
      for (int c = 0; c < 2; c++) {
        ol = __builtin_amdgcn_mfma_f32_16x16x32_bf16(onef.v, pf[c].v, ol, 0, 0, 0);
#pragma unroll
        for (int dt = 0; dt < 4; dt++) {
          const bf16x8 vv = *reinterpret_cast<const bf16x8*>(
              vb + (dt * 16 + l16) * 128 + (((c * 4 + grp) ^ sw) << 3));
          o[dt] = __builtin_amdgcn_mfma_f32_16x16x32_bf16(vv, pf[c].v, o[dt], 0, 0, 0);
        }
      }
    }
  }
  const int b = bh >> 4, h = bh & 15;
  const float rl = 1.0f / ol[0];
  const size_t orow = (size_t)(b * 2048 + q0 + l16) * 1024 + h * 64;
#pragma unroll
  for (int dt = 0; dt < 4; dt++) {
    uint2 ov = make_uint2(pkbf(o[dt][0] * rl, o[dt][1] * rl),
                          pkbf(o[dt][2] * rl, o[dt][3] * rl));
    *reinterpret_cast<uint2*>(&aout[orow + dt * 16 + grp * 4]) = ov;
  }
}

// ---------------- proj GEMM v2: 8-wave blocks, 32x32 per wave ----------------
// 512 threads; grid (mtile=x 32, ntile=y 16) = 512 blocks -> 2 blocks/CU = 16 waves/CU.
__global__ __launch_bounds__(512)
void gemm_proj(const ushort_t* __restrict__ A, const ushort_t* __restrict__ B,
               float* __restrict__ Cout, const float* __restrict__ bias) {
  const int K = 1024, N = 1024;
  __shared__ __align__(16) ushort_t smem[16384];   // 32KB: sA(16K)+sB(8K); sT aliases all
  ushort_t* sA = smem;
  ushort_t* sB = smem + 8192;
  const int m0 = blockIdx.x * 128, n0 = blockIdx.y * 64;
  const int tid = threadIdx.x;
  const int lane = tid & 63, w = tid >> 6;
  const int wm = (w >> 1) * 32, wn = (w & 1) * 32;
  const int grp = lane >> 4, l16 = lane & 15;
  const int r8 = lane >> 3;
  const int c8 = ((lane & 7) ^ r8) * 8;
  floatx4 acc[2][2] = {};
  for (int k0 = 0; k0 < K; k0 += 64) {
    __syncthreads();
#pragma unroll
    for (int i = 0; i < 2; i++) {
      const int j = w * 2 + i;
      gl2lds16(&A[(size_t)(m0 + j * 8 + r8) * K + k0 + c8], &sA[j * 512]);
    }
    gl2lds16(&B[(size_t)(n0 + w * 8 + r8) * K + k0 + c8], &sB[w * 512]);
    __syncthreads();
#pragma unroll
    for (int kk = 0; kk < 2; kk++) {
      bf16x8 af[2], bfr[2];
#pragma unroll
      for (int i = 0; i < 2; i++) {
        const int ra = wm + i * 16 + l16;
        af[i] = *reinterpret_cast<const bf16x8*>(
            &sA[ra * 64 + (((kk * 4 + grp) ^ (ra & 7)) << 3)]);
      }
#pragma unroll
      for (int j = 0; j < 2; j++) {
        const int rb = wn + j * 16 + l16;
        bfr[j] = *reinterpret_cast<const bf16x8*>(
            &sB[rb * 64 + (((kk * 4 + grp) ^ (rb & 7)) << 3)]);
      }
#pragma unroll
      for (int i = 0; i < 2; i++)
#pragma unroll
        for (int j = 0; j < 2; j++)
          acc[i][j] = __builtin_amdgcn_mfma_f32_16x16x32_bf16(af[i], bfr[j], acc[i][j], 0, 0, 0);
    }
  }
  __syncthreads();                 // K-loop LDS reads done before sT overwrites
  // phase A: bias + per-wave 32x32 fp32 tile (4KB at smem + w*4KB), swizzle by row&7
  float* sT = (float*)(smem + w * 2048);
  float bv[2];
#pragma unroll
  for (int j = 0; j < 2; j++) bv[j] = bias[n0 + wn + j * 16 + l16];
#pragma unroll
  for (int i = 0; i < 2; i++)
#pragma unroll
    for (int j = 0; j < 2; j++) {
      const int col = j * 16 + l16, c4 = col >> 2;
#pragma unroll
      for (int rr = 0; rr < 4; rr++) {
        const int row = i * 16 + grp * 4 + rr;
        sT[row * 32 + ((c4 ^ (row & 7)) << 2) + (col & 3)] = acc[i][j][rr] + bv[j];
      }
    }
  __builtin_amdgcn_s_waitcnt(0);   // per-wave tile: LDS writes before reads
  const int lr = lane >> 3, ch = lane & 7;
#pragma unroll
  for (int rg = 0; rg < 4; rg++) {
    const int row = rg * 8 + lr;
    float4 vvv = *(const float4*)&sT[row * 32 + ((ch ^ (row & 7)) << 2)];
    *reinterpret_cast<float4*>(&Cout[(size_t)(m0 + wm + row) * N + n0 + wn + ch * 4]) = vvv;
  }
}

extern "C" void kernel_launch(void* const* d_in, const int* in_sizes, int n_in,
                              void* d_out, int out_size, void* d_ws, size_t ws_size,
                              hipStream_t stream) {
  const float* x      = (const float*)d_in[0];   // [2,2048,1024]
  const float* pos    = (const float*)d_in[1];   // [2048,32]
  const float* qkv_w  = (const float*)d_in[2];   // [3072,1024]
  const float* q_nw   = (const float*)d_in[3];   // [64]
  const float* k_nw   = (const float*)d_in[4];   // [64]
  const float* proj_w = (const float*)d_in[5];   // [1024,1024]
  const float* proj_b = (const float*)d_in[6];   // [1024]
  float* out = (float*)d_out;                    // [2,2048,1024] fp32

  ushort_t* x_b     = (ushort_t*)d_ws;                         // 4096*1024
  ushort_t* qkvw_b  = x_b     + (size_t)4096 * 1024;           // 3072*1024
  ushort_t* projw_b = qkvw_b  + (size_t)3072 * 1024;           // 1024*1024
  ushort_t* q_r     = projw_b + (size_t)1024 * 1024;           // 32*2048*64
  ushort_t* k_r     = q_r     + (size_t)32 * 2048 * 64;
  ushort_t* v_t     = k_r     + (size_t)32 * 2048 * 64;
  ushort_t* a_out   = v_t     + (size_t)32 * 2048 * 64;        // 4096*1024
  float*    cs_tab  = (float*)(a_out + (size_t)4096 * 1024);   // 65536*2 fp32 (512KB)

  cast_all<<<8388608 / 4 / 256, 256, 0, stream>>>(x, qkv_w, proj_w, x_b, pos, cs_tab);

  gemm_qkv_fused<<<dim3(4096 / 128, 3072 / 128), 512, 0, stream>>>(
      x_b, qkvw_b, cs_tab, q_nw, k_nw, q_r, k_r, v_t);

  flash_attn<<<dim3(32, 2048 / 128), 512, 0, stream>>>(q_r, k_r, v_t, a_out);

  gemm_proj<<<dim3(4096 / 128, 1024 / 64), 512, 0, stream>>>(a_out, projw_b, out, proj_b);
}